// Round 2
// baseline (2417.687 us; speedup 1.0000x reference)
//
#include <hip/hip_runtime.h>
#include <hip/hip_bf16.h>
#include <cstddef>

#define KD 30      // knapsack constraints
#define KP 32      // padded
#define RD 500     // resources
#define RP 512     // padded
#define NITER 200

#define SWZ(x, imm) __int_as_float(__builtin_amdgcn_ds_swizzle(__float_as_int(x), (imm)))
#define RDL(x, l)   __int_as_float(__builtin_amdgcn_readlane(__float_as_int(x), (l)))

// ---------------------------------------------------------------------------
// prep1: S = I + 0.5 W W^T (30x30); SinvP = padded 32x32 S^{-1}; sc1 = S^{-1} c1
// where c1 = rowsum(W) - 2*cap.
// ---------------------------------------------------------------------------
__global__ __launch_bounds__(256) void prep1(
    const float* __restrict__ W, const float* __restrict__ cap,
    float* __restrict__ SinvP, float* __restrict__ sc1)
{
    __shared__ float S[KD][KD];
    __shared__ float Inv[KD][KD];
    __shared__ float c1s[KD];
    int tid = threadIdx.x;
    for (int p = tid; p < KD*KD; p += 256) {
        int a = p / KD, b = p % KD;
        float s = 0.f;
        for (int r = 0; r < RD; ++r) s = fmaf(W[a*RD+r], W[b*RD+r], s);
        S[a][b]  = 0.5f*s + (a==b ? 1.f : 0.f);
        Inv[a][b] = (a==b) ? 1.f : 0.f;
    }
    if (tid < KD) {
        float s = 0.f;
        for (int r = 0; r < RD; ++r) s += W[tid*RD+r];
        c1s[tid] = s - 2.f*cap[tid];
    }
    __syncthreads();
    // Gauss-Jordan (SPD, diagonally dominant -> no pivoting)
    for (int p = 0; p < KD; ++p) {
        float f = 0.f;
        if (tid < KD && tid != p) f = S[tid][p] / S[p][p];
        __syncthreads();
        if (tid < KD && tid != p) {
            for (int c = 0; c < KD; ++c) {
                S[tid][c]   -= f * S[p][c];
                Inv[tid][c] -= f * Inv[p][c];
            }
        }
        __syncthreads();
    }
    for (int p = tid; p < KP*KP; p += 256) {
        int a2 = p >> 5, b2 = p & 31;
        float v = 0.f;
        if (a2 < KD && b2 < KD) v = Inv[a2][b2] / S[a2][a2];
        SinvP[p] = v;
    }
    if (tid < KP) {
        float s = 0.f;
        if (tid < KD)
            for (int nn = 0; nn < KD; ++nn) s = fmaf(Inv[tid][nn] / S[tid][tid], c1s[nn], s);
        sc1[tid] = s;
    }
}

// ---------------------------------------------------------------------------
// prep2: Mp = S^{-1} W, W32 = W, both zero-padded to [32][512]
// ---------------------------------------------------------------------------
__global__ __launch_bounds__(256) void prep2(
    const float* __restrict__ W, const float* __restrict__ SinvP,
    float* __restrict__ Mp, float* __restrict__ W32)
{
    int idx = blockIdx.x*256 + threadIdx.x;   // 0..16383
    int m = idx >> 9, j = idx & (RP-1);
    float wv = (m < KD && j < RD) ? W[m*RD + j] : 0.f;
    W32[idx] = wv;
    float s = 0.f;
    if (j < RD) {
        for (int nn = 0; nn < KD; ++nn) s = fmaf(SinvP[(m<<5)+nn], W[nn*RD + j], s);
    }
    Mp[idx] = s;   // rows m>=30: SinvP row is zero -> 0
}

// ---------------------------------------------------------------------------
// gemm_nt: C[M][ldo] = act(A[M][K] @ B[Nrows][K]^T + bias); 64x64 tile, BK=16
// act=1: leaky relu 0.1. Columns n>=Nreal written 0.
// ---------------------------------------------------------------------------
__global__ __launch_bounds__(256) void gemm_nt(
    const float* __restrict__ A, const float* __restrict__ B,
    const float* __restrict__ bias, float* __restrict__ C,
    int K, int Nreal, int ldo, int act)
{
    __shared__ float As[16][68];
    __shared__ float Bs[16][68];
    int tid = threadIdx.x;
    int bm = blockIdx.y << 6;
    int bn = blockIdx.x << 6;
    int lrow = tid >> 2;
    int lkq  = (tid & 3) << 2;
    int m0 = (tid >> 4) << 2;
    int n0 = (tid & 15) << 2;

    float acc[4][4];
    #pragma unroll
    for (int j = 0; j < 4; ++j) {
        int nn = bn + n0 + j;
        float bv = (nn < Nreal) ? bias[nn] : 0.f;
        #pragma unroll
        for (int i = 0; i < 4; ++i) acc[i][j] = bv;
    }

    const float* Ap = A + (size_t)(bm + lrow)*K + lkq;
    int brow = bn + lrow;
    bool bok = brow < Nreal;
    const float* Bp = B + (size_t)brow*K + lkq;

    for (int k0 = 0; k0 < K; k0 += 16) {
        float4 av = *(const float4*)(Ap + k0);
        float4 bv = bok ? *(const float4*)(Bp + k0) : make_float4(0.f,0.f,0.f,0.f);
        __syncthreads();
        As[lkq+0][lrow] = av.x; As[lkq+1][lrow] = av.y;
        As[lkq+2][lrow] = av.z; As[lkq+3][lrow] = av.w;
        Bs[lkq+0][lrow] = bv.x; Bs[lkq+1][lrow] = bv.y;
        Bs[lkq+2][lrow] = bv.z; Bs[lkq+3][lrow] = bv.w;
        __syncthreads();
        #pragma unroll
        for (int kk = 0; kk < 16; ++kk) {
            float a4[4], b4[4];
            *(float4*)a4 = *(const float4*)&As[kk][m0];
            *(float4*)b4 = *(const float4*)&Bs[kk][n0];
            #pragma unroll
            for (int i = 0; i < 4; ++i)
                #pragma unroll
                for (int j = 0; j < 4; ++j)
                    acc[i][j] = fmaf(a4[i], b4[j], acc[i][j]);
        }
    }

    #pragma unroll
    for (int i = 0; i < 4; ++i) {
        #pragma unroll
        for (int j = 0; j < 4; ++j) {
            int nn = bn + n0 + j;
            float v = acc[i][j];
            if (act) v = v > 0.f ? v : 0.1f*v;
            if (nn >= Nreal) v = 0.f;
            C[(size_t)(bm + m0 + i)*ldo + nn] = v;
        }
    }
}

// ---------------------------------------------------------------------------
// admm2: q-form ADMM.  q <- x + min(q,0),  x = P(w+|q|)/2 + d0, unrolled as:
//   e_r = w_r+|q_r|; e_t = |q_t|; e_s = |q_s|; a = 0.5(e_r - e_t)
//   y1  = M a + S^{-1} e_s + sc1        (M = S^{-1} W)
//   g   = W^T y1
//   x_r = 0.5 a - 0.25 g + 0.5 ; x_t = 1 - x_r ; x_s = 0.5(e_s - y1)
// 2 rows per wave, 2 waves per block, 4 rows/block, 256 blocks.
// Lane l: j-slices {4l..4l+3, 256+4l..256+4l+3} of both rows; s-comp (l&31)
// of row (l>>5). y1 lands distributed: lane l holds y1[l>>5][l&31].
// ---------------------------------------------------------------------------
__global__ __launch_bounds__(128) void admm2(
    const float* __restrict__ cost, const float* __restrict__ Mp,
    const float* __restrict__ W32, const float* __restrict__ SinvP,
    const float* __restrict__ sc1, float* __restrict__ out)
{
    __shared__ float Ml[KP][RP];   // 64 KB
    __shared__ float Wl[KP][RP];   // 64 KB
    int tid = threadIdx.x;
    {
        const float4* msrc = (const float4*)Mp;
        const float4* wsrc = (const float4*)W32;
        float4* md = (float4*)&Ml[0][0];
        float4* wd = (float4*)&Wl[0][0];
        for (int i = tid; i < KP*RP/4; i += 128) { md[i] = msrc[i]; wd[i] = wsrc[i]; }
    }
    __syncthreads();

    int lane = tid & 63;
    int wid  = tid >> 6;
    int myr  = lane >> 5;
    int nidx = lane & 31;
    int r0   = (blockIdx.x << 2) + (wid << 1);   // rows r0, r0+1

    float sv[KP];
    #pragma unroll
    for (int m = 0; m < KP; m += 4)
        *(float4*)&sv[m] = *(const float4*)&SinvP[(nidx << 5) + m];
    float sc1v = sc1[nidx];

    float wr0[8], wr1[8];
    {
        const float* c0 = cost + (size_t)r0*RP + 4*lane;
        *(float4*)&wr0[0] = *(const float4*)c0;
        *(float4*)&wr0[4] = *(const float4*)(c0 + 256);
        *(float4*)&wr1[0] = *(const float4*)(c0 + RP);
        *(float4*)&wr1[4] = *(const float4*)(c0 + RP + 256);
    }

    float qr0[8], qr1[8], qt0[8], qt1[8];
    #pragma unroll
    for (int j = 0; j < 8; ++j) { qr0[j]=0.f; qr1[j]=0.f; qt0[j]=0.f; qt1[j]=0.f; }
    float qs = 0.f;
    float xr0[8], xr1[8], xs0 = 0.f;

    #pragma unroll 1
    for (int it = 0; it < NITER; ++it) {
        float a0[8], a1[8];
        #pragma unroll
        for (int j = 0; j < 8; ++j) {
            a0[j] = 0.5f * ((wr0[j] + fabsf(qr0[j])) - fabsf(qt0[j]));
            a1[j] = 0.5f * ((wr1[j] + fabsf(qr1[j])) - fabsf(qt1[j]));
        }
        float es  = fabsf(qs);
        float es0 = (myr == 0) ? es : 0.f;
        float es1 = es - es0;

        float y1v = 0.f;
        #pragma unroll
        for (int c = 0; c < 4; ++c) {
            float p0[8], p1[8];
            #pragma unroll
            for (int ml = 0; ml < 8; ++ml) {
                int m = (c << 3) + ml;
                float4 u0 = *(const float4*)&Ml[m][4*lane];
                float4 u1 = *(const float4*)&Ml[m][256 + 4*lane];
                float s0 = sv[m] * es0;
                s0 = fmaf(u0.x, a0[0], s0); s0 = fmaf(u0.y, a0[1], s0);
                s0 = fmaf(u0.z, a0[2], s0); s0 = fmaf(u0.w, a0[3], s0);
                s0 = fmaf(u1.x, a0[4], s0); s0 = fmaf(u1.y, a0[5], s0);
                s0 = fmaf(u1.z, a0[6], s0); s0 = fmaf(u1.w, a0[7], s0);
                p0[ml] = s0;
                float s1 = sv[m] * es1;
                s1 = fmaf(u0.x, a1[0], s1); s1 = fmaf(u0.y, a1[1], s1);
                s1 = fmaf(u0.z, a1[2], s1); s1 = fmaf(u0.w, a1[3], s1);
                s1 = fmaf(u1.x, a1[4], s1); s1 = fmaf(u1.y, a1[5], s1);
                s1 = fmaf(u1.z, a1[6], s1); s1 = fmaf(u1.w, a1[7], s1);
                p1[ml] = s1;
            }
            // reduce-scatter: 16 values (2 rows x 8 m) -> 1 per lane
            float ka[8];
            #pragma unroll
            for (int ml = 0; ml < 8; ++ml) {                 // xor 32 (row bit)
                float snd = myr ? p0[ml] : p1[ml];
                float rcv = __shfl_xor(snd, 32, 64);
                ka[ml] = (myr ? p1[ml] : p0[ml]) + rcv;
            }
            float kb[4];
            #pragma unroll
            for (int h = 0; h < 4; ++h) {                    // xor 1 (m bit0)
                float snd = (lane & 1) ? ka[2*h] : ka[2*h+1];
                float rcv = SWZ(snd, 0x041F);
                kb[h] = ((lane & 1) ? ka[2*h+1] : ka[2*h]) + rcv;
            }
            float kc[2];
            #pragma unroll
            for (int dd = 0; dd < 2; ++dd) {                 // xor 2 (m bit1)
                float snd = (lane & 2) ? kb[2*dd] : kb[2*dd+1];
                float rcv = SWZ(snd, 0x081F);
                kc[dd] = ((lane & 2) ? kb[2*dd+1] : kb[2*dd]) + rcv;
            }
            float snd = (lane & 4) ? kc[0] : kc[1];          // xor 4 (m bit2)
            float kd = ((lane & 4) ? kc[1] : kc[0]) + SWZ(snd, 0x101F);
            kd += SWZ(kd, 0x201F);                           // xor 8 (sum)
            kd += SWZ(kd, 0x401F);                           // xor 16 (sum)
            y1v = (((lane >> 3) & 3) == c) ? kd : y1v;
        }
        y1v += sc1v;   // lane l now holds y1[l>>5][l&31]

        float g0[8], g1[8];
        #pragma unroll
        for (int j = 0; j < 8; ++j) { g0[j]=0.f; g1[j]=0.f; }
        #pragma unroll
        for (int k = 0; k < KD; ++k) {
            float yk0 = RDL(y1v, k);
            float yk1 = RDL(y1v, 32 + k);
            float4 u0 = *(const float4*)&Wl[k][4*lane];
            float4 u1 = *(const float4*)&Wl[k][256 + 4*lane];
            g0[0] = fmaf(u0.x, yk0, g0[0]); g0[1] = fmaf(u0.y, yk0, g0[1]);
            g0[2] = fmaf(u0.z, yk0, g0[2]); g0[3] = fmaf(u0.w, yk0, g0[3]);
            g0[4] = fmaf(u1.x, yk0, g0[4]); g0[5] = fmaf(u1.y, yk0, g0[5]);
            g0[6] = fmaf(u1.z, yk0, g0[6]); g0[7] = fmaf(u1.w, yk0, g0[7]);
            g1[0] = fmaf(u0.x, yk1, g1[0]); g1[1] = fmaf(u0.y, yk1, g1[1]);
            g1[2] = fmaf(u0.z, yk1, g1[2]); g1[3] = fmaf(u0.w, yk1, g1[3]);
            g1[4] = fmaf(u1.x, yk1, g1[4]); g1[5] = fmaf(u1.y, yk1, g1[5]);
            g1[6] = fmaf(u1.z, yk1, g1[6]); g1[7] = fmaf(u1.w, yk1, g1[7]);
        }
        #pragma unroll
        for (int j = 0; j < 8; ++j) {
            float x0 = fmaf(g0[j], -0.25f, fmaf(a0[j], 0.5f, 0.5f));
            xr0[j] = x0;
            qr0[j] = x0 + fminf(qr0[j], 0.f);
            qt0[j] = (1.f - x0) + fminf(qt0[j], 0.f);
            float x1 = fmaf(g1[j], -0.25f, fmaf(a1[j], 0.5f, 0.5f));
            xr1[j] = x1;
            qr1[j] = x1 + fminf(qr1[j], 0.f);
            qt1[j] = (1.f - x1) + fminf(qt1[j], 0.f);
        }
        xs0 = 0.5f * (es - y1v);
        qs  = xs0 + fminf(qs, 0.f);
    }

    // write x = [x_r(500), x_s(30), x_t(500)] for rows r0, r0+1
    float* o0 = out + (size_t)r0 * 1030;
    float* o1 = o0 + 1030;
    #pragma unroll
    for (int c2 = 0; c2 < 2; ++c2) {
        #pragma unroll
        for (int q = 0; q < 4; ++q) {
            int j  = c2*256 + 4*lane + q;
            int jj = c2*4 + q;
            if (j < RD) {
                o0[j]       = xr0[jj];
                o0[530 + j] = 1.f - xr0[jj];
                o1[j]       = xr1[jj];
                o1[530 + j] = 1.f - xr1[jj];
            }
        }
    }
    if (nidx < KD) {
        float* om = myr ? o1 : o0;
        om[500 + nidx] = xs0;
    }
}

// ---------------------------------------------------------------------------
extern "C" void kernel_launch(void* const* d_in, const int* in_sizes, int n_in,
                              void* d_out, int out_size, void* d_ws, size_t ws_size,
                              hipStream_t stream)
{
    const float* d   = (const float*)d_in[0];
    const float* W1  = (const float*)d_in[1];
    const float* b1  = (const float*)d_in[2];
    const float* W2  = (const float*)d_in[3];
    const float* b2  = (const float*)d_in[4];
    const float* W3  = (const float*)d_in[5];
    const float* b3  = (const float*)d_in[6];
    const float* Wm  = (const float*)d_in[7];
    const float* cap = (const float*)d_in[8];

    float* ws    = (float*)d_ws;
    float* h1    = ws;                        // [1024][3200]
    float* h2    = ws + 3276800;              // [1024][3200]
    float* cost  = ws;                        // [1024][512] (reuses h1)
    float* Mp    = ws + 2*3276800;            // [32][512]
    float* W32   = Mp + KP*RP;                // [32][512]
    float* SinvP = W32 + KP*RP;               // [32][32]
    float* sc1   = SinvP + KP*KP;             // [32]
    float* outp  = (float*)d_out;             // [1024][1030]

    hipLaunchKernelGGL(prep1, dim3(1),  dim3(256), 0, stream, Wm, cap, SinvP, sc1);
    hipLaunchKernelGGL(prep2, dim3(64), dim3(256), 0, stream, Wm, SinvP, Mp, W32);
    hipLaunchKernelGGL(gemm_nt, dim3(50,16), dim3(256), 0, stream, d,  W1, b1, h1,   32,   3200, 3200, 1);
    hipLaunchKernelGGL(gemm_nt, dim3(50,16), dim3(256), 0, stream, h1, W2, b2, h2,   3200, 3200, 3200, 1);
    hipLaunchKernelGGL(gemm_nt, dim3(8,16),  dim3(256), 0, stream, h2, W3, b3, cost, 3200, 500,  512,  0);
    hipLaunchKernelGGL(admm2, dim3(256), dim3(128), 0, stream, cost, Mp, W32, SinvP, sc1, outp);
}

// Round 3
// 1608.490 us; speedup vs baseline: 1.5031x; 1.5031x over previous
//
#include <hip/hip_runtime.h>
#include <hip/hip_bf16.h>
#include <cstddef>

#define KD 30      // knapsack constraints
#define KP 32      // padded
#define RD 500     // resources
#define RP 512     // padded
#define NITER 200

#define SWZ(x, imm) __int_as_float(__builtin_amdgcn_ds_swizzle(__float_as_int(x), (imm)))
#define RDL(x, l)   __int_as_float(__builtin_amdgcn_readlane(__float_as_int(x), (l)))

// ---------------------------------------------------------------------------
// prep1: S = I + 0.5 W W^T (30x30); SinvG = padded [32][32] S^{-1};
// c1g[m] = rowsum(W)[m] - 2*cap[m] (zero-padded); Wpad = W zero-padded [32][512]
// ---------------------------------------------------------------------------
__global__ __launch_bounds__(256) void prep1(
    const float* __restrict__ W, const float* __restrict__ cap,
    float* __restrict__ SinvG, float* __restrict__ c1g, float* __restrict__ Wpad)
{
    __shared__ float S[KD][KD];
    __shared__ float Inv[KD][KD];
    int tid = threadIdx.x;
    for (int p = tid; p < KD*KD; p += 256) {
        int a = p / KD, b = p % KD;
        float s = 0.f;
        for (int r = 0; r < RD; ++r) s = fmaf(W[a*RD+r], W[b*RD+r], s);
        S[a][b]  = 0.5f*s + (a==b ? 1.f : 0.f);
        Inv[a][b] = (a==b) ? 1.f : 0.f;
    }
    __syncthreads();
    // Gauss-Jordan (SPD, diagonally dominant -> no pivoting)
    for (int p = 0; p < KD; ++p) {
        float f = 0.f;
        if (tid < KD && tid != p) f = S[tid][p] / S[p][p];
        __syncthreads();
        if (tid < KD && tid != p) {
            for (int c = 0; c < KD; ++c) {
                S[tid][c]   -= f * S[p][c];
                Inv[tid][c] -= f * Inv[p][c];
            }
        }
        __syncthreads();
    }
    for (int p = tid; p < KP*KP; p += 256) {
        int a2 = p >> 5, b2 = p & 31;
        SinvG[p] = (a2 < KD && b2 < KD) ? Inv[a2][b2] / S[a2][a2] : 0.f;
    }
    if (tid < KP) {
        float s = 0.f;
        if (tid < KD) {
            for (int r = 0; r < RD; ++r) s += W[tid*RD+r];
            s -= 2.f*cap[tid];
        }
        c1g[tid] = s;
    }
    for (int p = tid; p < KP*RP; p += 256) {
        int m = p >> 9, j = p & (RP-1);
        Wpad[p] = (m < KD && j < RD) ? W[m*RD + j] : 0.f;
    }
}

// ---------------------------------------------------------------------------
// gemm128: C[M][ldo] = act(A[M][K] @ B[Nrows][K]^T + bias); 128x128 tile, BK=16,
// 256 threads, 8x8 micro-tile. act=1: leaky relu 0.1. Cols n>=Nreal -> 0.
// ---------------------------------------------------------------------------
__global__ __launch_bounds__(256) void gemm128(
    const float* __restrict__ A, const float* __restrict__ B,
    const float* __restrict__ bias, float* __restrict__ C,
    int K, int Nreal, int ldo, int act)
{
    __shared__ float As[16][128];
    __shared__ float Bs[16][128];
    int tid = threadIdx.x;
    int bm = blockIdx.y << 7;
    int bn = blockIdx.x << 7;
    int srow = tid >> 1;            // 0..127
    int skq  = (tid & 1) << 3;      // 0 or 8
    int m0 = (tid >> 4) << 3;       // 0..120
    int n0 = (tid & 15) << 3;       // 0..120

    float acc[8][8];
    #pragma unroll
    for (int j = 0; j < 8; ++j) {
        int nn = bn + n0 + j;
        float bv = (nn < Nreal) ? bias[nn] : 0.f;
        #pragma unroll
        for (int i = 0; i < 8; ++i) acc[i][j] = bv;
    }

    const float* Ap = A + (size_t)(bm + srow)*K + skq;
    int brow = bn + srow;
    bool bok = brow < Nreal;
    const float* Bp = B + (size_t)brow*K + skq;

    for (int k0 = 0; k0 < K; k0 += 16) {
        float4 av0 = *(const float4*)(Ap + k0);
        float4 av1 = *(const float4*)(Ap + k0 + 4);
        float4 bv0 = make_float4(0.f,0.f,0.f,0.f), bv1 = bv0;
        if (bok) { bv0 = *(const float4*)(Bp + k0); bv1 = *(const float4*)(Bp + k0 + 4); }
        __syncthreads();
        As[skq+0][srow]=av0.x; As[skq+1][srow]=av0.y; As[skq+2][srow]=av0.z; As[skq+3][srow]=av0.w;
        As[skq+4][srow]=av1.x; As[skq+5][srow]=av1.y; As[skq+6][srow]=av1.z; As[skq+7][srow]=av1.w;
        Bs[skq+0][srow]=bv0.x; Bs[skq+1][srow]=bv0.y; Bs[skq+2][srow]=bv0.z; Bs[skq+3][srow]=bv0.w;
        Bs[skq+4][srow]=bv1.x; Bs[skq+5][srow]=bv1.y; Bs[skq+6][srow]=bv1.z; Bs[skq+7][srow]=bv1.w;
        __syncthreads();
        #pragma unroll
        for (int kk = 0; kk < 16; ++kk) {
            float a8[8], b8[8];
            *(float4*)&a8[0] = *(const float4*)&As[kk][m0];
            *(float4*)&a8[4] = *(const float4*)&As[kk][m0+4];
            *(float4*)&b8[0] = *(const float4*)&Bs[kk][n0];
            *(float4*)&b8[4] = *(const float4*)&Bs[kk][n0+4];
            #pragma unroll
            for (int i = 0; i < 8; ++i)
                #pragma unroll
                for (int j = 0; j < 8; ++j)
                    acc[i][j] = fmaf(a8[i], b8[j], acc[i][j]);
        }
    }

    #pragma unroll
    for (int i = 0; i < 8; ++i) {
        float* crow = C + (size_t)(bm + m0 + i)*ldo + bn + n0;
        float o[8];
        #pragma unroll
        for (int j = 0; j < 8; ++j) {
            int nn = bn + n0 + j;
            float v = acc[i][j];
            if (act) v = v > 0.f ? v : 0.1f*v;
            if (nn >= Nreal) v = 0.f;
            o[j] = v;
        }
        *(float4*)crow       = *(const float4*)&o[0];
        *(float4*)(crow + 4) = *(const float4*)&o[4];
    }
}

// ---------------------------------------------------------------------------
// admm3: q-form ADMM, 2 rows per BLOCK, cols split across 2 waves.
//   e_r = w_r+|q_r|; e_t = |q_t|; e_s = |q_s|; a = 0.5(e_r - e_t)
//   t̂  = W a + e_s + c1   (reduce-scatter in-wave, then cross-wave combine)
//   y1  = S^{-1} t̂        (readlane broadcast + Sinv from LDS)
//   g   = W^T y1
//   x_r = 0.5a - 0.25g + 0.5 ; x_t = 1-x_r ; x_s = 0.5(e_s - y1)
//   q <- x + min(q,0)
// Lane l of wave w owns cols 256w+4l..+3 of BOTH rows; s-comp (l&31) of row l>>5.
// 512 blocks x 128 thr; ~70KB LDS -> 2 blocks/CU, 4 waves/CU.
// ---------------------------------------------------------------------------
__global__ __launch_bounds__(128) void admm3(
    const float* __restrict__ cost, const float* __restrict__ Wpad,
    const float* __restrict__ SinvG, const float* __restrict__ c1g,
    float* __restrict__ out)
{
    __shared__ float Wl[KP][RP];        // 64 KB
    __shared__ float SiP[KP][33];       // padded vs bank conflicts
    __shared__ float red[2][2][64];     // cross-wave combine, dbuf by it&1
    int tid = threadIdx.x;
    {
        float4* wd = (float4*)&Wl[0][0];
        const float4* wsrc = (const float4*)Wpad;
        for (int i = tid; i < KP*RP/4; i += 128) wd[i] = wsrc[i];
        for (int i = tid; i < KP*KP; i += 128) SiP[i>>5][i&31] = SinvG[i];
    }
    __syncthreads();

    int lane = tid & 63;
    int wid  = tid >> 6;
    int myr  = lane >> 5;
    int nidx = lane & 31;
    int r0   = blockIdx.x << 1;              // rows r0, r0+1
    int colb = (wid << 8) + (lane << 2);     // 4 owned cols

    float c1v = c1g[nidx];
    float wr0[4], wr1[4];
    *(float4*)wr0 = *(const float4*)(cost + (size_t)r0*RP + colb);
    *(float4*)wr1 = *(const float4*)(cost + (size_t)(r0+1)*RP + colb);

    float qr0[4], qr1[4], qt0[4], qt1[4];
    #pragma unroll
    for (int j = 0; j < 4; ++j) { qr0[j]=0.f; qr1[j]=0.f; qt0[j]=0.f; qt1[j]=0.f; }
    float qs = 0.f;
    float xr0[4], xr1[4], xs = 0.f;

    #pragma unroll 1
    for (int it = 0; it < NITER; ++it) {
        float a0[4], a1[4];
        #pragma unroll
        for (int j = 0; j < 4; ++j) {
            a0[j] = 0.5f * ((wr0[j] + fabsf(qr0[j])) - fabsf(qt0[j]));
            a1[j] = 0.5f * ((wr1[j] + fabsf(qr1[j])) - fabsf(qt1[j]));
        }
        float es = fabsf(qs);

        // ---- t̂-partials over owned cols + in-wave reduce-scatter ----
        float y1v = 0.f;
        #pragma unroll
        for (int c = 0; c < 4; ++c) {
            float p0[8], p1[8];
            #pragma unroll
            for (int ml = 0; ml < 8; ++ml) {
                int m = (c << 3) + ml;
                float4 u = *(const float4*)&Wl[m][colb];
                p0[ml] = fmaf(u.w,a0[3],fmaf(u.z,a0[2],fmaf(u.y,a0[1],u.x*a0[0])));
                p1[ml] = fmaf(u.w,a1[3],fmaf(u.z,a1[2],fmaf(u.y,a1[1],u.x*a1[0])));
            }
            float ka[8];
            #pragma unroll
            for (int ml = 0; ml < 8; ++ml) {                 // xor 32 (row bit)
                float snd = myr ? p0[ml] : p1[ml];
                float rcv = __shfl_xor(snd, 32, 64);
                ka[ml] = (myr ? p1[ml] : p0[ml]) + rcv;
            }
            float kb[4];
            #pragma unroll
            for (int h = 0; h < 4; ++h) {                    // xor 1
                float snd = (lane & 1) ? ka[2*h] : ka[2*h+1];
                float rcv = SWZ(snd, 0x041F);
                kb[h] = ((lane & 1) ? ka[2*h+1] : ka[2*h]) + rcv;
            }
            float kc[2];
            #pragma unroll
            for (int dd = 0; dd < 2; ++dd) {                 // xor 2
                float snd = (lane & 2) ? kb[2*dd] : kb[2*dd+1];
                float rcv = SWZ(snd, 0x081F);
                kc[dd] = ((lane & 2) ? kb[2*dd+1] : kb[2*dd]) + rcv;
            }
            float snd2 = (lane & 4) ? kc[0] : kc[1];         // xor 4
            float kd = ((lane & 4) ? kc[1] : kc[0]) + SWZ(snd2, 0x101F);
            kd += SWZ(kd, 0x201F);                           // xor 8 (sum)
            kd += SWZ(kd, 0x401F);                           // xor 16 (sum)
            y1v = (((lane >> 3) & 3) == c) ? kd : y1v;
        }
        // ---- cross-wave combine (one barrier/iter, dbuf) ----
        red[it & 1][wid][lane] = y1v;
        __syncthreads();
        float th = y1v + red[it & 1][wid ^ 1][lane] + es + c1v;  // t̂[myr][nidx]
        // ---- y1 = Sinv * t̂  (distributed same layout) ----
        float y1 = 0.f;
        #pragma unroll
        for (int m = 0; m < KD; ++m) {
            float s0 = RDL(th, m);
            float s1 = RDL(th, 32 + m);
            float tb = myr ? s1 : s0;
            y1 = fmaf(SiP[nidx][m], tb, y1);
        }
        xs = 0.5f * (es - y1);
        qs = xs + fminf(qs, 0.f);
        // ---- g = W^T y1 over owned cols ----
        float g0[4], g1[4];
        #pragma unroll
        for (int j = 0; j < 4; ++j) { g0[j]=0.f; g1[j]=0.f; }
        #pragma unroll
        for (int k = 0; k < KD; ++k) {
            float yk0 = RDL(y1, k);
            float yk1 = RDL(y1, 32 + k);
            float4 u = *(const float4*)&Wl[k][colb];
            g0[0]=fmaf(u.x,yk0,g0[0]); g0[1]=fmaf(u.y,yk0,g0[1]);
            g0[2]=fmaf(u.z,yk0,g0[2]); g0[3]=fmaf(u.w,yk0,g0[3]);
            g1[0]=fmaf(u.x,yk1,g1[0]); g1[1]=fmaf(u.y,yk1,g1[1]);
            g1[2]=fmaf(u.z,yk1,g1[2]); g1[3]=fmaf(u.w,yk1,g1[3]);
        }
        // ---- x, q updates ----
        #pragma unroll
        for (int j = 0; j < 4; ++j) {
            float x0 = fmaf(g0[j], -0.25f, fmaf(a0[j], 0.5f, 0.5f));
            xr0[j] = x0;
            qr0[j] = x0 + fminf(qr0[j], 0.f);
            qt0[j] = (1.f - x0) + fminf(qt0[j], 0.f);
            float x1 = fmaf(g1[j], -0.25f, fmaf(a1[j], 0.5f, 0.5f));
            xr1[j] = x1;
            qr1[j] = x1 + fminf(qr1[j], 0.f);
            qt1[j] = (1.f - x1) + fminf(qt1[j], 0.f);
        }
    }

    // ---- write x = [x_r(500), x_s(30), x_t(500)] for rows r0, r0+1 ----
    float* o0 = out + (size_t)r0 * 1030;
    float* o1 = o0 + 1030;
    #pragma unroll
    for (int q = 0; q < 4; ++q) {
        int col = colb + q;
        if (col < RD) {
            o0[col]       = xr0[q];
            o0[530 + col] = 1.f - xr0[q];
            o1[col]       = xr1[q];
            o1[530 + col] = 1.f - xr1[q];
        }
    }
    if (wid == 0 && nidx < KD) {
        (myr ? o1 : o0)[500 + nidx] = xs;
    }
}

// ---------------------------------------------------------------------------
extern "C" void kernel_launch(void* const* d_in, const int* in_sizes, int n_in,
                              void* d_out, int out_size, void* d_ws, size_t ws_size,
                              hipStream_t stream)
{
    const float* d   = (const float*)d_in[0];
    const float* W1  = (const float*)d_in[1];
    const float* b1  = (const float*)d_in[2];
    const float* W2  = (const float*)d_in[3];
    const float* b2  = (const float*)d_in[4];
    const float* W3  = (const float*)d_in[5];
    const float* b3  = (const float*)d_in[6];
    const float* Wm  = (const float*)d_in[7];
    const float* cap = (const float*)d_in[8];

    float* ws    = (float*)d_ws;
    float* h1    = ws;                        // [1024][3200]
    float* h2    = ws + 3276800;              // [1024][3200]
    float* cost  = ws;                        // [1024][512] (reuses h1; h1 dead)
    float* Wpad  = ws + 2*3276800;            // [32][512]
    float* SinvG = Wpad + KP*RP;              // [32][32]
    float* c1g   = SinvG + KP*KP;             // [32]
    float* outp  = (float*)d_out;             // [1024][1030]

    hipLaunchKernelGGL(prep1, dim3(1), dim3(256), 0, stream, Wm, cap, SinvG, c1g, Wpad);
    hipLaunchKernelGGL(gemm128, dim3(25,8), dim3(256), 0, stream, d,  W1, b1, h1,   32,   3200, 3200, 1);
    hipLaunchKernelGGL(gemm128, dim3(25,8), dim3(256), 0, stream, h1, W2, b2, h2,   3200, 3200, 3200, 1);
    hipLaunchKernelGGL(gemm128, dim3(4,8),  dim3(256), 0, stream, h2, W3, b3, cost, 3200, 500,  512,  0);
    hipLaunchKernelGGL(admm3, dim3(512), dim3(128), 0, stream, cost, Wpad, SinvG, c1g, outp);
}

// Round 4
// 1380.084 us; speedup vs baseline: 1.7518x; 1.1655x over previous
//
#include <hip/hip_runtime.h>
#include <hip/hip_bf16.h>
#include <cstddef>

#define KD 30      // knapsack constraints
#define KP 32      // padded
#define RD 500     // resources
#define RP 512     // padded
#define NITER 200

#define SWZ(x, imm) __int_as_float(__builtin_amdgcn_ds_swizzle(__float_as_int(x), (imm)))
#define RDL(x, l)   __int_as_float(__builtin_amdgcn_readlane(__float_as_int(x), (l)))

// ---------------------------------------------------------------------------
// prep1: S = I + 0.5 W W^T (30x30); SinvG = padded [32][32] S^{-1};
// c1g[m] = rowsum(W)[m] - 2*cap[m] (zero-padded); Wpad = W zero-padded [32][512]
// ---------------------------------------------------------------------------
__global__ __launch_bounds__(256) void prep1(
    const float* __restrict__ W, const float* __restrict__ cap,
    float* __restrict__ SinvG, float* __restrict__ c1g, float* __restrict__ Wpad)
{
    __shared__ float S[KD][KD];
    __shared__ float Inv[KD][KD];
    int tid = threadIdx.x;
    for (int p = tid; p < KD*KD; p += 256) {
        int a = p / KD, b = p % KD;
        float s = 0.f;
        for (int r = 0; r < RD; ++r) s = fmaf(W[a*RD+r], W[b*RD+r], s);
        S[a][b]  = 0.5f*s + (a==b ? 1.f : 0.f);
        Inv[a][b] = (a==b) ? 1.f : 0.f;
    }
    __syncthreads();
    for (int p = 0; p < KD; ++p) {
        float f = 0.f;
        if (tid < KD && tid != p) f = S[tid][p] / S[p][p];
        __syncthreads();
        if (tid < KD && tid != p) {
            for (int c = 0; c < KD; ++c) {
                S[tid][c]   -= f * S[p][c];
                Inv[tid][c] -= f * Inv[p][c];
            }
        }
        __syncthreads();
    }
    for (int p = tid; p < KP*KP; p += 256) {
        int a2 = p >> 5, b2 = p & 31;
        SinvG[p] = (a2 < KD && b2 < KD) ? Inv[a2][b2] / S[a2][a2] : 0.f;
    }
    if (tid < KP) {
        float s = 0.f;
        if (tid < KD) {
            for (int r = 0; r < RD; ++r) s += W[tid*RD+r];
            s -= 2.f*cap[tid];
        }
        c1g[tid] = s;
    }
    for (int p = tid; p < KP*RP; p += 256) {
        int m = p >> 9, j = p & (RP-1);
        Wpad[p] = (m < KD && j < RD) ? W[m*RD + j] : 0.f;
    }
}

// ---------------------------------------------------------------------------
// gemm_big: C[M][ldo] = act(A[M][K] @ B[N][K]^T + bias); BM=64, BN=128, BK=16,
// 256 thr, micro 4x(4+4). Conflict-free LDS; register-prefetch double buffer.
// ---------------------------------------------------------------------------
__global__ __launch_bounds__(256) void gemm_big(
    const float* __restrict__ A, const float* __restrict__ B,
    const float* __restrict__ bias, float* __restrict__ C,
    int K, int Nreal, int ldo, int act)
{
    __shared__ float As[16][64];
    __shared__ float Bs[16][128];
    int tid = threadIdx.x;
    int bm = blockIdx.y << 6;
    int bn = blockIdx.x << 7;
    int arow = tid & 63,  aq = (tid >> 6) << 2;    // A stage: row, k-offset
    int brw  = tid & 127, bq = (tid >> 7) << 3;    // B stage: row, k-offset
    int m0 = (tid >> 4) << 2, n0 = (tid & 15) << 2;

    const float* Ap = A + (size_t)(bm + arow)*K + aq;
    int brow = bn + brw;
    bool bok = brow < Nreal;
    const float* Bp = B + (size_t)brow*K + bq;

    float4 av, bva, bvb;
    const float4 z4 = make_float4(0.f,0.f,0.f,0.f);
    av  = *(const float4*)Ap;
    bva = bok ? *(const float4*)(Bp)     : z4;
    bvb = bok ? *(const float4*)(Bp + 4) : z4;

    float acc[4][8];
    #pragma unroll
    for (int j = 0; j < 8; ++j) {
        int nn = bn + (j < 4 ? n0 + j : 64 + n0 + (j - 4));
        float bv = (nn < Nreal) ? bias[nn] : 0.f;
        #pragma unroll
        for (int i = 0; i < 4; ++i) acc[i][j] = bv;
    }

    for (int k0 = 0; k0 < K; k0 += 16) {
        __syncthreads();
        As[aq+0][arow]=av.x;  As[aq+1][arow]=av.y;  As[aq+2][arow]=av.z;  As[aq+3][arow]=av.w;
        Bs[bq+0][brw]=bva.x; Bs[bq+1][brw]=bva.y; Bs[bq+2][brw]=bva.z; Bs[bq+3][brw]=bva.w;
        Bs[bq+4][brw]=bvb.x; Bs[bq+5][brw]=bvb.y; Bs[bq+6][brw]=bvb.z; Bs[bq+7][brw]=bvb.w;
        __syncthreads();
        if (k0 + 16 < K) {
            av  = *(const float4*)(Ap + k0 + 16);
            bva = bok ? *(const float4*)(Bp + k0 + 16) : z4;
            bvb = bok ? *(const float4*)(Bp + k0 + 20) : z4;
        }
        #pragma unroll
        for (int kk = 0; kk < 16; ++kk) {
            float a4[4], ba[4], bb[4];
            *(float4*)a4 = *(const float4*)&As[kk][m0];
            *(float4*)ba = *(const float4*)&Bs[kk][n0];
            *(float4*)bb = *(const float4*)&Bs[kk][64 + n0];
            #pragma unroll
            for (int i = 0; i < 4; ++i) {
                #pragma unroll
                for (int j = 0; j < 4; ++j) {
                    acc[i][j]   = fmaf(a4[i], ba[j], acc[i][j]);
                    acc[i][j+4] = fmaf(a4[i], bb[j], acc[i][j+4]);
                }
            }
        }
    }

    #pragma unroll
    for (int i = 0; i < 4; ++i) {
        float* crow = C + (size_t)(bm + m0 + i)*ldo + bn;
        float o[8];
        #pragma unroll
        for (int j = 0; j < 8; ++j) {
            int nn = bn + (j < 4 ? n0 + j : 64 + n0 + (j - 4));
            float v = acc[i][j];
            if (act) v = v > 0.f ? v : 0.1f*v;
            if (nn >= Nreal) v = 0.f;
            o[j] = v;
        }
        *(float4*)(crow + n0)      = *(const float4*)&o[0];
        *(float4*)(crow + 64 + n0) = *(const float4*)&o[4];
    }
}

// ---------------------------------------------------------------------------
// gemm_sm: same but BN=64, micro 4x4 (for the 512-wide cost layer)
// ---------------------------------------------------------------------------
__global__ __launch_bounds__(256) void gemm_sm(
    const float* __restrict__ A, const float* __restrict__ B,
    const float* __restrict__ bias, float* __restrict__ C,
    int K, int Nreal, int ldo, int act)
{
    __shared__ float As[16][64];
    __shared__ float Bs[16][64];
    int tid = threadIdx.x;
    int bm = blockIdx.y << 6;
    int bn = blockIdx.x << 6;
    int arow = tid & 63, aq = (tid >> 6) << 2;
    int m0 = (tid >> 4) << 2, n0 = (tid & 15) << 2;

    const float* Ap = A + (size_t)(bm + arow)*K + aq;
    int brow = bn + arow;
    bool bok = brow < Nreal;
    const float* Bp = B + (size_t)brow*K + aq;

    float4 av, bv;
    const float4 z4 = make_float4(0.f,0.f,0.f,0.f);
    av = *(const float4*)Ap;
    bv = bok ? *(const float4*)Bp : z4;

    float acc[4][4];
    #pragma unroll
    for (int j = 0; j < 4; ++j) {
        int nn = bn + n0 + j;
        float bb = (nn < Nreal) ? bias[nn] : 0.f;
        #pragma unroll
        for (int i = 0; i < 4; ++i) acc[i][j] = bb;
    }

    for (int k0 = 0; k0 < K; k0 += 16) {
        __syncthreads();
        As[aq+0][arow]=av.x; As[aq+1][arow]=av.y; As[aq+2][arow]=av.z; As[aq+3][arow]=av.w;
        Bs[aq+0][arow]=bv.x; Bs[aq+1][arow]=bv.y; Bs[aq+2][arow]=bv.z; Bs[aq+3][arow]=bv.w;
        __syncthreads();
        if (k0 + 16 < K) {
            av = *(const float4*)(Ap + k0 + 16);
            bv = bok ? *(const float4*)(Bp + k0 + 16) : z4;
        }
        #pragma unroll
        for (int kk = 0; kk < 16; ++kk) {
            float a4[4], b4[4];
            *(float4*)a4 = *(const float4*)&As[kk][m0];
            *(float4*)b4 = *(const float4*)&Bs[kk][n0];
            #pragma unroll
            for (int i = 0; i < 4; ++i)
                #pragma unroll
                for (int j = 0; j < 4; ++j)
                    acc[i][j] = fmaf(a4[i], b4[j], acc[i][j]);
        }
    }

    #pragma unroll
    for (int i = 0; i < 4; ++i) {
        float* crow = C + (size_t)(bm + m0 + i)*ldo + bn;
        float o[4];
        #pragma unroll
        for (int j = 0; j < 4; ++j) {
            int nn = bn + n0 + j;
            float v = acc[i][j];
            if (act) v = v > 0.f ? v : 0.1f*v;
            if (nn >= Nreal) v = 0.f;
            o[j] = v;
        }
        *(float4*)(crow + n0) = *(const float4*)&o[0];
    }
}

// ---------------------------------------------------------------------------
// admm4: q-form ADMM. 2 rows per block, 4 waves split cols 4-way (2 cols/lane).
//   e_r=w_r+|q_r|; e_t=|q_t|; e_s=|q_s|; a=0.5(e_r-e_t)
//   t̂ = W a + e_s + c1 (in-wave butterfly reduce-scatter + 4-wave LDS combine)
//   y1 = S^{-1} t̂ (sv regs + readlane);  g = W^T y1
//   x_r=0.5a-0.25g+0.5; x_t=1-x_r; x_s=0.5(e_s-y1);  q <- x + min(q,0)
// Lane l of wave w: cols {128w+2l, 128w+2l+1} of both rows; s-comp (l&31) of
// row l>>5 (all waves replicate s-state identically).
// 512 blocks x 256 thr; 66KB LDS -> 2 blocks/CU = 8 waves/CU = 2/SIMD.
// ---------------------------------------------------------------------------
__global__ __launch_bounds__(256) void admm4(
    const float* __restrict__ cost, const float* __restrict__ Wpad,
    const float* __restrict__ SinvG, const float* __restrict__ c1g,
    float* __restrict__ out)
{
    __shared__ float Wl[KP][RP];       // 64 KB
    __shared__ float red[2][4][64];    // 2 KB, dbuf by it&1
    int tid = threadIdx.x;
    {
        float4* wd = (float4*)&Wl[0][0];
        const float4* wsrc = (const float4*)Wpad;
        for (int i = tid; i < KP*RP/4; i += 256) wd[i] = wsrc[i];
    }
    __syncthreads();

    int lane = tid & 63;
    int wid  = tid >> 6;
    int myr  = lane >> 5;
    int nidx = lane & 31;
    int r0   = blockIdx.x << 1;
    int colb = (wid << 7) + (lane << 1);   // 2 owned cols

    float sv[KP];                          // Sinv row nidx
    #pragma unroll
    for (int m = 0; m < KP; m += 4)
        *(float4*)&sv[m] = *(const float4*)&SinvG[(nidx << 5) + m];
    float c1v = c1g[nidx];

    float wr0[2], wr1[2];
    *(float2*)wr0 = *(const float2*)(cost + (size_t)r0*RP + colb);
    *(float2*)wr1 = *(const float2*)(cost + (size_t)(r0+1)*RP + colb);

    float qr0[2]={0.f,0.f}, qr1[2]={0.f,0.f}, qt0[2]={0.f,0.f}, qt1[2]={0.f,0.f};
    float qs = 0.f, xs = 0.f;
    float xr0[2], xr1[2];

    bool sb0 = lane & 1, sb1 = lane & 2, sb2 = lane & 4, sb3 = lane & 8, sb4 = lane & 16;

    #pragma unroll 1
    for (int it = 0; it < NITER; ++it) {
        float a0[2], a1[2];
        #pragma unroll
        for (int j = 0; j < 2; ++j) {
            a0[j] = 0.5f * ((wr0[j] + fabsf(qr0[j])) - fabsf(qt0[j]));
            a1[j] = 0.5f * ((wr1[j] + fabsf(qr1[j])) - fabsf(qt1[j]));
        }
        float es = fabsf(qs);

        // ---- per-lane partials over 2 owned cols, all 32 m ----
        float p0[32], p1[32];
        #pragma unroll
        for (int m = 0; m < KP; ++m) {
            float2 u = *(const float2*)&Wl[m][colb];
            p0[m] = fmaf(u.y, a0[1], u.x * a0[0]);
            p1[m] = fmaf(u.y, a1[1], u.x * a1[0]);
        }
        // ---- butterfly reduce-scatter (m-bits 0..4 intra-32, then row bit) ----
        float qa0[16], qa1[16];
        #pragma unroll
        for (int j = 0; j < 16; ++j) {
            float k0v = sb0 ? p0[2*j+1] : p0[2*j];
            float s0v = sb0 ? p0[2*j]   : p0[2*j+1];
            qa0[j] = k0v + SWZ(s0v, 0x041F);
            float k1v = sb0 ? p1[2*j+1] : p1[2*j];
            float s1v = sb0 ? p1[2*j]   : p1[2*j+1];
            qa1[j] = k1v + SWZ(s1v, 0x041F);
        }
        float ra0[8], ra1[8];
        #pragma unroll
        for (int j = 0; j < 8; ++j) {
            float k0v = sb1 ? qa0[2*j+1] : qa0[2*j];
            float s0v = sb1 ? qa0[2*j]   : qa0[2*j+1];
            ra0[j] = k0v + SWZ(s0v, 0x081F);
            float k1v = sb1 ? qa1[2*j+1] : qa1[2*j];
            float s1v = sb1 ? qa1[2*j]   : qa1[2*j+1];
            ra1[j] = k1v + SWZ(s1v, 0x081F);
        }
        float ta0[4], ta1[4];
        #pragma unroll
        for (int j = 0; j < 4; ++j) {
            float k0v = sb2 ? ra0[2*j+1] : ra0[2*j];
            float s0v = sb2 ? ra0[2*j]   : ra0[2*j+1];
            ta0[j] = k0v + SWZ(s0v, 0x101F);
            float k1v = sb2 ? ra1[2*j+1] : ra1[2*j];
            float s1v = sb2 ? ra1[2*j]   : ra1[2*j+1];
            ta1[j] = k1v + SWZ(s1v, 0x101F);
        }
        float ua0[2], ua1[2];
        #pragma unroll
        for (int j = 0; j < 2; ++j) {
            float k0v = sb3 ? ta0[2*j+1] : ta0[2*j];
            float s0v = sb3 ? ta0[2*j]   : ta0[2*j+1];
            ua0[j] = k0v + SWZ(s0v, 0x201F);
            float k1v = sb3 ? ta1[2*j+1] : ta1[2*j];
            float s1v = sb3 ? ta1[2*j]   : ta1[2*j+1];
            ua1[j] = k1v + SWZ(s1v, 0x201F);
        }
        float v0, v1;
        {
            float k0v = sb4 ? ua0[1] : ua0[0];
            float s0v = sb4 ? ua0[0] : ua0[1];
            v0 = k0v + SWZ(s0v, 0x401F);
            float k1v = sb4 ? ua1[1] : ua1[0];
            float s1v = sb4 ? ua1[0] : ua1[1];
            v1 = k1v + SWZ(s1v, 0x401F);
        }
        // cross-half: keep own row, swap the other
        float snd = myr ? v0 : v1;
        float thw = (myr ? v1 : v0) + __shfl_xor(snd, 32, 64);

        // ---- cross-wave combine (one barrier/iter, dbuf) ----
        int buf = it & 1;
        red[buf][wid][lane] = thw;
        __syncthreads();
        float th = red[buf][0][lane] + red[buf][1][lane]
                 + red[buf][2][lane] + red[buf][3][lane] + es + c1v;

        // ---- y1 = Sinv * t̂ (distributed: lane holds row lane>>5, n=lane&31) ----
        float y1 = 0.f;
        #pragma unroll
        for (int m = 0; m < KD; ++m) {
            float t0 = RDL(th, m);
            float t1 = RDL(th, 32 + m);
            y1 = fmaf(sv[m], myr ? t1 : t0, y1);
        }
        xs = 0.5f * (es - y1);
        qs = xs + fminf(qs, 0.f);

        // ---- g = W^T y1 over owned cols ----
        float g0[2] = {0.f,0.f}, g1[2] = {0.f,0.f};
        #pragma unroll
        for (int k = 0; k < KD; ++k) {
            float yk0 = RDL(y1, k);
            float yk1 = RDL(y1, 32 + k);
            float2 u = *(const float2*)&Wl[k][colb];
            g0[0] = fmaf(u.x, yk0, g0[0]); g0[1] = fmaf(u.y, yk0, g0[1]);
            g1[0] = fmaf(u.x, yk1, g1[0]); g1[1] = fmaf(u.y, yk1, g1[1]);
        }
        // ---- x, q updates ----
        #pragma unroll
        for (int j = 0; j < 2; ++j) {
            float x0 = fmaf(g0[j], -0.25f, fmaf(a0[j], 0.5f, 0.5f));
            xr0[j] = x0;
            qr0[j] = x0 + fminf(qr0[j], 0.f);
            qt0[j] = (1.f - x0) + fminf(qt0[j], 0.f);
            float x1 = fmaf(g1[j], -0.25f, fmaf(a1[j], 0.5f, 0.5f));
            xr1[j] = x1;
            qr1[j] = x1 + fminf(qr1[j], 0.f);
            qt1[j] = (1.f - x1) + fminf(qt1[j], 0.f);
        }
    }

    // ---- write x = [x_r(500), x_s(30), x_t(500)] ----
    float* o0 = out + (size_t)r0 * 1030;
    float* o1 = o0 + 1030;
    #pragma unroll
    for (int q = 0; q < 2; ++q) {
        int col = colb + q;
        if (col < RD) {
            o0[col]       = xr0[q];
            o0[530 + col] = 1.f - xr0[q];
            o1[col]       = xr1[q];
            o1[530 + col] = 1.f - xr1[q];
        }
    }
    if (wid == 0 && nidx < KD) {
        (myr ? o1 : o0)[500 + nidx] = xs;
    }
}

// ---------------------------------------------------------------------------
extern "C" void kernel_launch(void* const* d_in, const int* in_sizes, int n_in,
                              void* d_out, int out_size, void* d_ws, size_t ws_size,
                              hipStream_t stream)
{
    const float* d   = (const float*)d_in[0];
    const float* W1  = (const float*)d_in[1];
    const float* b1  = (const float*)d_in[2];
    const float* W2  = (const float*)d_in[3];
    const float* b2  = (const float*)d_in[4];
    const float* W3  = (const float*)d_in[5];
    const float* b3  = (const float*)d_in[6];
    const float* Wm  = (const float*)d_in[7];
    const float* cap = (const float*)d_in[8];

    float* ws    = (float*)d_ws;
    float* h1    = ws;                        // [1024][3200]
    float* h2    = ws + 3276800;              // [1024][3200]
    float* cost  = ws;                        // [1024][512] (reuses h1; h1 dead)
    float* Wpad  = ws + 2*3276800;            // [32][512]
    float* SinvG = Wpad + KP*RP;              // [32][32]
    float* c1g   = SinvG + KP*KP;             // [32]
    float* outp  = (float*)d_out;             // [1024][1030]

    hipLaunchKernelGGL(prep1, dim3(1), dim3(256), 0, stream, Wm, cap, SinvG, c1g, Wpad);
    hipLaunchKernelGGL(gemm_big, dim3(25,16), dim3(256), 0, stream, d,  W1, b1, h1,   32,   3200, 3200, 1);
    hipLaunchKernelGGL(gemm_big, dim3(25,16), dim3(256), 0, stream, h1, W2, b2, h2,   3200, 3200, 3200, 1);
    hipLaunchKernelGGL(gemm_sm,  dim3(8,16),  dim3(256), 0, stream, h2, W3, b3, cost, 3200, 500,  512,  0);
    hipLaunchKernelGGL(admm4, dim3(512), dim3(256), 0, stream, cost, Wpad, SinvG, c1g, outp);
}

// Round 5
// 1017.852 us; speedup vs baseline: 2.3753x; 1.3559x over previous
//
#include <hip/hip_runtime.h>
#include <hip/hip_bf16.h>
#include <cstddef>

#define KD 30      // knapsack constraints
#define KP 32      // padded
#define RD 500     // resources
#define RP 512     // padded
#define NITER 200

#define SWZ(x, imm) __int_as_float(__builtin_amdgcn_ds_swizzle(__float_as_int(x), (imm)))
#define RDL(x, l)   __int_as_float(__builtin_amdgcn_readlane(__float_as_int(x), (l)))

typedef unsigned short u16;
typedef __attribute__((ext_vector_type(8))) short short8v;
typedef __attribute__((ext_vector_type(4))) float f32x4;

__device__ inline u16 f2bf(float x) {
    unsigned b = __float_as_uint(x);
    return (u16)((b + 0x7fffu + ((b >> 16) & 1u)) >> 16);
}
__device__ inline float bf2f(u16 u) { return __uint_as_float(((unsigned)u) << 16); }

__device__ inline void gload_lds16(const void* g, void* l) {
    __builtin_amdgcn_global_load_lds(
        (const __attribute__((address_space(1))) void*)g,
        (__attribute__((address_space(3))) void*)l, 16, 0, 0);
}

// ---------------------------------------------------------------------------
// prep1: S = I + 0.5 W W^T (30x30); SinvG = padded [32][32] S^{-1};
// c1g[m] = rowsum(W)[m] - 2*cap[m]; Wpad = W zero-padded [32][512]
// ---------------------------------------------------------------------------
__global__ __launch_bounds__(256) void prep1(
    const float* __restrict__ W, const float* __restrict__ cap,
    float* __restrict__ SinvG, float* __restrict__ c1g, float* __restrict__ Wpad)
{
    __shared__ float S[KD][KD];
    __shared__ float Inv[KD][KD];
    int tid = threadIdx.x;
    for (int p = tid; p < KD*KD; p += 256) {
        int a = p / KD, b = p % KD;
        float s = 0.f;
        for (int r = 0; r < RD; ++r) s = fmaf(W[a*RD+r], W[b*RD+r], s);
        S[a][b]  = 0.5f*s + (a==b ? 1.f : 0.f);
        Inv[a][b] = (a==b) ? 1.f : 0.f;
    }
    __syncthreads();
    for (int p = 0; p < KD; ++p) {
        float f = 0.f;
        if (tid < KD && tid != p) f = S[tid][p] / S[p][p];
        __syncthreads();
        if (tid < KD && tid != p) {
            for (int c = 0; c < KD; ++c) {
                S[tid][c]   -= f * S[p][c];
                Inv[tid][c] -= f * Inv[p][c];
            }
        }
        __syncthreads();
    }
    for (int p = tid; p < KP*KP; p += 256) {
        int a2 = p >> 5, b2 = p & 31;
        SinvG[p] = (a2 < KD && b2 < KD) ? Inv[a2][b2] / S[a2][a2] : 0.f;
    }
    if (tid < KP) {
        float s = 0.f;
        if (tid < KD) {
            for (int r = 0; r < RD; ++r) s += W[tid*RD+r];
            s -= 2.f*cap[tid];
        }
        c1g[tid] = s;
    }
    for (int p = tid; p < KP*RP; p += 256) {
        int m = p >> 9, j = p & (RP-1);
        Wpad[p] = (m < KD && j < RD) ? W[m*RD + j] : 0.f;
    }
}

// ---------------------------------------------------------------------------
// gemm1p: h1 = lrelu(d[1024][32] @ W1[3200][32]^T + b1) -> bf16 hi/lo planes
// 64x64 tile, whole K=32 in LDS, 4x4 micro-tile.
// ---------------------------------------------------------------------------
__global__ __launch_bounds__(256) void gemm1p(
    const float* __restrict__ A, const float* __restrict__ B,
    const float* __restrict__ bias, u16* __restrict__ Chi, u16* __restrict__ Clo)
{
    __shared__ float As[32][64];
    __shared__ float Bs[32][64];
    int tid = threadIdx.x;
    int bm = blockIdx.y << 6, bn = blockIdx.x << 6;
    int r = tid & 63, kq = (tid >> 6) << 3;
    {
        const float* ap = A + (size_t)(bm + r)*32 + kq;
        const float* bp = B + (size_t)(bn + r)*32 + kq;
        float a8[8], b8[8];
        *(float4*)&a8[0] = *(const float4*)ap;  *(float4*)&a8[4] = *(const float4*)(ap+4);
        *(float4*)&b8[0] = *(const float4*)bp;  *(float4*)&b8[4] = *(const float4*)(bp+4);
        #pragma unroll
        for (int i = 0; i < 8; ++i) { As[kq+i][r] = a8[i]; Bs[kq+i][r] = b8[i]; }
    }
    __syncthreads();
    int m0 = (tid >> 4) << 2, n0 = (tid & 15) << 2;
    float acc[4][4];
    #pragma unroll
    for (int i = 0; i < 4; ++i)
        #pragma unroll
        for (int j = 0; j < 4; ++j) acc[i][j] = 0.f;
    #pragma unroll
    for (int kk = 0; kk < 32; ++kk) {
        float a4[4], b4[4];
        *(float4*)a4 = *(const float4*)&As[kk][m0];
        *(float4*)b4 = *(const float4*)&Bs[kk][n0];
        #pragma unroll
        for (int i = 0; i < 4; ++i)
            #pragma unroll
            for (int j = 0; j < 4; ++j)
                acc[i][j] = fmaf(a4[i], b4[j], acc[i][j]);
    }
    #pragma unroll
    for (int i = 0; i < 4; ++i) {
        #pragma unroll
        for (int j = 0; j < 4; ++j) {
            int col = bn + n0 + j;
            float v = acc[i][j] + bias[col];
            v = v > 0.f ? v : 0.1f*v;
            u16 h = f2bf(v);
            u16 l2 = f2bf(v - bf2f(h));
            size_t o = (size_t)(bm + m0 + i)*3200 + col;
            Chi[o] = h; Clo[o] = l2;
        }
    }
}

// ---------------------------------------------------------------------------
// mfma_nt: C = A @ B^T with A given as bf16 hi/lo planes [M][Kfull] (K-contig)
// and B fp32 [Nrows][Kfull] converted to hi/lo bf16 on the fly.
// Split product: hi*hi + hi*lo + lo*hi (3 MFMA per frag pair).
// BM=128, BN=128 or 64; BK=32; 4 waves, wave tile 64x(BN/2); dbuf LDS.
// LDS chunk layout (16B = 8 bf16): chunk = k4*ROWS + row -> conflict-free
// b128 frag reads and linear global_load_lds A staging.
// OM=0: lrelu+bias, write bf16 hi/lo planes. OM=1: raw fp32 partial
// (split-K via blockIdx.z; kOff = z*kLen; dest offset z*1024*512).
// ---------------------------------------------------------------------------
template<int BN, int OM>
__global__ __launch_bounds__(256) void mfma_nt(
    const u16* __restrict__ Ahi, const u16* __restrict__ Alo,
    const float* __restrict__ Bf, const float* __restrict__ bias,
    u16* __restrict__ Chi, u16* __restrict__ Clo, float* __restrict__ Cf,
    int Kfull, int kLen, int Nrows, int ldo)
{
    constexpr int BK = 32;
    constexpr int NTN = (BN == 128) ? 4 : 2;
    constexpr int NB  = (BN == 128) ? 16 : 8;   // staged floats per lane
    __shared__ __align__(16) u16 Ah[2][4096], Al[2][4096];
    __shared__ __align__(16) u16 Bh[2][BN*BK], Bl[2][BN*BK];

    const int tid = threadIdx.x, lane = tid & 63, w = tid >> 6;
    const int lr = lane & 15, lk = lane >> 4;
    const int bm = blockIdx.y << 7;
    const int bn = blockIdx.x * BN;
    const int wm = w >> 1, wn = w & 1;
    const int kOff = blockIdx.z * kLen;
    const int NTS = kLen / BK;

    f32x4 acc[4][NTN];
    #pragma unroll
    for (int i = 0; i < 4; ++i)
        #pragma unroll
        for (int j = 0; j < NTN; ++j) acc[i][j] = (f32x4){0.f, 0.f, 0.f, 0.f};

    // B staging geometry
    int brow, bko, bchunk0;
    if (BN == 128) { brow = w*32 + (lane & 31); bko = (lane >> 5) * 16; bchunk0 = ((lane >> 5)*2)*128 + brow; }
    else           { brow = w*16 + (lane & 15); bko = (lane >> 4) * 8;  bchunk0 = (lane >> 4)*64  + brow; }
    const float* bptr = Bf + (size_t)(bn + brow)*Kfull + kOff + bko;
    const bool bok = (bn + brow) < Nrows;

    const u16* ahp = Ahi + (size_t)(bm + lane)*Kfull + kOff + 8*w;
    const u16* alp = Alo + (size_t)(bm + lane)*Kfull + kOff + 8*w;
    const size_t arstride = (size_t)64 * Kfull;

    auto stageA = [&](int buf, int t) {
        int k0 = t * BK;
        gload_lds16(ahp + k0,            &Ah[buf][(w*128     ) * 8]);
        gload_lds16(ahp + k0 + arstride, &Ah[buf][(w*128 + 64) * 8]);
        gload_lds16(alp + k0,            &Al[buf][(w*128     ) * 8]);
        gload_lds16(alp + k0 + arstride, &Al[buf][(w*128 + 64) * 8]);
    };
    auto loadB = [&](int t, float (&arr)[NB]) {
        #pragma unroll
        for (int i = 0; i < NB; i += 4)
            *(float4*)&arr[i] = bok ? *(const float4*)(bptr + t*BK + i)
                                    : make_float4(0.f, 0.f, 0.f, 0.f);
    };
    auto writeB = [&](int buf, float (&arr)[NB]) {
        u16 hh[NB], ll[NB];
        #pragma unroll
        for (int i = 0; i < NB; ++i) {
            hh[i] = f2bf(arr[i]);
            ll[i] = f2bf(arr[i] - bf2f(hh[i]));
        }
        #pragma unroll
        for (int c = 0; c < NB/8; ++c) {
            short8v vh, vl;
            #pragma unroll
            for (int j = 0; j < 8; ++j) { vh[j] = (short)hh[c*8+j]; vl[j] = (short)ll[c*8+j]; }
            int ch = bchunk0 + c*128;     // only c=0 used when BN=64
            *(short8v*)&Bh[buf][ch*8] = vh;
            *(short8v*)&Bl[buf][ch*8] = vl;
        }
    };
    auto compute = [&](int buf) {
        short8v ah[4], al[4];
        #pragma unroll
        for (int mt = 0; mt < 4; ++mt) {
            int c = (lk*128 + wm*64 + mt*16 + lr) * 8;
            ah[mt] = *(const short8v*)&Ah[buf][c];
            al[mt] = *(const short8v*)&Al[buf][c];
        }
        #pragma unroll
        for (int nt = 0; nt < NTN; ++nt) {
            int c = (lk*BN + wn*(NTN*16) + nt*16 + lr) * 8;
            short8v bh = *(const short8v*)&Bh[buf][c];
            short8v bl = *(const short8v*)&Bl[buf][c];
            #pragma unroll
            for (int mt = 0; mt < 4; ++mt) {
                acc[mt][nt] = __builtin_amdgcn_mfma_f32_16x16x32_bf16(ah[mt], bh, acc[mt][nt], 0, 0, 0);
                acc[mt][nt] = __builtin_amdgcn_mfma_f32_16x16x32_bf16(ah[mt], bl, acc[mt][nt], 0, 0, 0);
                acc[mt][nt] = __builtin_amdgcn_mfma_f32_16x16x32_bf16(al[mt], bh, acc[mt][nt], 0, 0, 0);
            }
        }
    };

    float bcur[NB], bnxt[NB];
    stageA(0, 0); loadB(0, bcur); writeB(0, bcur);
    int cur = 0;
    for (int t = 0; t < NTS; ++t) {
        __syncthreads();
        if (t + 1 < NTS) { stageA(cur ^ 1, t + 1); loadB(t + 1, bnxt); }
        compute(cur);
        if (t + 1 < NTS) writeB(cur ^ 1, bnxt);
        cur ^= 1;
    }

    if (OM == 0) {
        #pragma unroll
        for (int nt = 0; nt < NTN; ++nt) {
            int col = bn + wn*(NTN*16) + nt*16 + lr;
            float bia = bias[col];
            #pragma unroll
            for (int mt = 0; mt < 4; ++mt) {
                #pragma unroll
                for (int j = 0; j < 4; ++j) {
                    int row = bm + wm*64 + mt*16 + lk*4 + j;
                    float v = acc[mt][nt][j] + bia;
                    v = v > 0.f ? v : 0.1f*v;
                    u16 h = f2bf(v);
                    u16 l2 = f2bf(v - bf2f(h));
                    size_t o = (size_t)row*ldo + col;
                    Chi[o] = h; Clo[o] = l2;
                }
            }
        }
    } else {
        float* cf = Cf + (size_t)blockIdx.z * (1024*512);
        #pragma unroll
        for (int nt = 0; nt < NTN; ++nt) {
            int col = bn + wn*(NTN*16) + nt*16 + lr;
            #pragma unroll
            for (int mt = 0; mt < 4; ++mt) {
                #pragma unroll
                for (int j = 0; j < 4; ++j) {
                    int row = bm + wm*64 + mt*16 + lk*4 + j;
                    cf[(size_t)row*ldo + col] = acc[mt][nt][j];
                }
            }
        }
    }
}

// ---------------------------------------------------------------------------
// reduce3: cost[1024][512] = sum_sk partials + b3 (cols<500), else 0
// ---------------------------------------------------------------------------
__global__ __launch_bounds__(256) void reduce3(
    const float* __restrict__ part, const float* __restrict__ b3,
    float* __restrict__ cost)
{
    int i = blockIdx.x*256 + threadIdx.x;    // 0..524287
    int col = i & 511;
    float v = part[i] + part[i + 524288];
    cost[i] = (col < RD) ? v + b3[col] : 0.f;
}

// ---------------------------------------------------------------------------
// admm4: q-form ADMM (unchanged from round 4).
// ---------------------------------------------------------------------------
__global__ __launch_bounds__(256) void admm4(
    const float* __restrict__ cost, const float* __restrict__ Wpad,
    const float* __restrict__ SinvG, const float* __restrict__ c1g,
    float* __restrict__ out)
{
    __shared__ float Wl[KP][RP];       // 64 KB
    __shared__ float red[2][4][64];    // 2 KB, dbuf by it&1
    int tid = threadIdx.x;
    {
        float4* wd = (float4*)&Wl[0][0];
        const float4* wsrc = (const float4*)Wpad;
        for (int i = tid; i < KP*RP/4; i += 256) wd[i] = wsrc[i];
    }
    __syncthreads();

    int lane = tid & 63;
    int wid  = tid >> 6;
    int myr  = lane >> 5;
    int nidx = lane & 31;
    int r0   = blockIdx.x << 1;
    int colb = (wid << 7) + (lane << 1);   // 2 owned cols

    float sv[KP];                          // Sinv row nidx
    #pragma unroll
    for (int m = 0; m < KP; m += 4)
        *(float4*)&sv[m] = *(const float4*)&SinvG[(nidx << 5) + m];
    float c1v = c1g[nidx];

    float wr0[2], wr1[2];
    *(float2*)wr0 = *(const float2*)(cost + (size_t)r0*RP + colb);
    *(float2*)wr1 = *(const float2*)(cost + (size_t)(r0+1)*RP + colb);

    float qr0[2]={0.f,0.f}, qr1[2]={0.f,0.f}, qt0[2]={0.f,0.f}, qt1[2]={0.f,0.f};
    float qs = 0.f, xs = 0.f;
    float xr0[2], xr1[2];

    bool sb0 = lane & 1, sb1 = lane & 2, sb2 = lane & 4, sb3 = lane & 8, sb4 = lane & 16;

    #pragma unroll 1
    for (int it = 0; it < NITER; ++it) {
        float a0[2], a1[2];
        #pragma unroll
        for (int j = 0; j < 2; ++j) {
            a0[j] = 0.5f * ((wr0[j] + fabsf(qr0[j])) - fabsf(qt0[j]));
            a1[j] = 0.5f * ((wr1[j] + fabsf(qr1[j])) - fabsf(qt1[j]));
        }
        float es = fabsf(qs);

        float p0[32], p1[32];
        #pragma unroll
        for (int m = 0; m < KP; ++m) {
            float2 u = *(const float2*)&Wl[m][colb];
            p0[m] = fmaf(u.y, a0[1], u.x * a0[0]);
            p1[m] = fmaf(u.y, a1[1], u.x * a1[0]);
        }
        float qa0[16], qa1[16];
        #pragma unroll
        for (int j = 0; j < 16; ++j) {
            float k0v = sb0 ? p0[2*j+1] : p0[2*j];
            float s0v = sb0 ? p0[2*j]   : p0[2*j+1];
            qa0[j] = k0v + SWZ(s0v, 0x041F);
            float k1v = sb0 ? p1[2*j+1] : p1[2*j];
            float s1v = sb0 ? p1[2*j]   : p1[2*j+1];
            qa1[j] = k1v + SWZ(s1v, 0x041F);
        }
        float ra0[8], ra1[8];
        #pragma unroll
        for (int j = 0; j < 8; ++j) {
            float k0v = sb1 ? qa0[2*j+1] : qa0[2*j];
            float s0v = sb1 ? qa0[2*j]   : qa0[2*j+1];
            ra0[j] = k0v + SWZ(s0v, 0x081F);
            float k1v = sb1 ? qa1[2*j+1] : qa1[2*j];
            float s1v = sb1 ? qa1[2*j]   : qa1[2*j+1];
            ra1[j] = k1v + SWZ(s1v, 0x081F);
        }
        float ta0[4], ta1[4];
        #pragma unroll
        for (int j = 0; j < 4; ++j) {
            float k0v = sb2 ? ra0[2*j+1] : ra0[2*j];
            float s0v = sb2 ? ra0[2*j]   : ra0[2*j+1];
            ta0[j] = k0v + SWZ(s0v, 0x101F);
            float k1v = sb2 ? ra1[2*j+1] : ra1[2*j];
            float s1v = sb2 ? ra1[2*j]   : ra1[2*j+1];
            ta1[j] = k1v + SWZ(s1v, 0x101F);
        }
        float ua0[2], ua1[2];
        #pragma unroll
        for (int j = 0; j < 2; ++j) {
            float k0v = sb3 ? ta0[2*j+1] : ta0[2*j];
            float s0v = sb3 ? ta0[2*j]   : ta0[2*j+1];
            ua0[j] = k0v + SWZ(s0v, 0x201F);
            float k1v = sb3 ? ta1[2*j+1] : ta1[2*j];
            float s1v = sb3 ? ta1[2*j]   : ta1[2*j+1];
            ua1[j] = k1v + SWZ(s1v, 0x201F);
        }
        float v0, v1;
        {
            float k0v = sb4 ? ua0[1] : ua0[0];
            float s0v = sb4 ? ua0[0] : ua0[1];
            v0 = k0v + SWZ(s0v, 0x401F);
            float k1v = sb4 ? ua1[1] : ua1[0];
            float s1v = sb4 ? ua1[0] : ua1[1];
            v1 = k1v + SWZ(s1v, 0x401F);
        }
        float snd = myr ? v0 : v1;
        float thw = (myr ? v1 : v0) + __shfl_xor(snd, 32, 64);

        int buf = it & 1;
        red[buf][wid][lane] = thw;
        __syncthreads();
        float th = red[buf][0][lane] + red[buf][1][lane]
                 + red[buf][2][lane] + red[buf][3][lane] + es + c1v;

        float y1 = 0.f;
        #pragma unroll
        for (int m = 0; m < KD; ++m) {
            float t0 = RDL(th, m);
            float t1 = RDL(th, 32 + m);
            y1 = fmaf(sv[m], myr ? t1 : t0, y1);
        }
        xs = 0.5f * (es - y1);
        qs = xs + fminf(qs, 0.f);

        float g0[2] = {0.f,0.f}, g1[2] = {0.f,0.f};
        #pragma unroll
        for (int k = 0; k < KD; ++k) {
            float yk0 = RDL(y1, k);
            float yk1 = RDL(y1, 32 + k);
            float2 u = *(const float2*)&Wl[k][colb];
            g0[0] = fmaf(u.x, yk0, g0[0]); g0[1] = fmaf(u.y, yk0, g0[1]);
            g1[0] = fmaf(u.x, yk1, g1[0]); g1[1] = fmaf(u.y, yk1, g1[1]);
        }
        #pragma unroll
        for (int j = 0; j < 2; ++j) {
            float x0 = fmaf(g0[j], -0.25f, fmaf(a0[j], 0.5f, 0.5f));
            xr0[j] = x0;
            qr0[j] = x0 + fminf(qr0[j], 0.f);
            qt0[j] = (1.f - x0) + fminf(qt0[j], 0.f);
            float x1 = fmaf(g1[j], -0.25f, fmaf(a1[j], 0.5f, 0.5f));
            xr1[j] = x1;
            qr1[j] = x1 + fminf(qr1[j], 0.f);
            qt1[j] = (1.f - x1) + fminf(qt1[j], 0.f);
        }
    }

    float* o0 = out + (size_t)r0 * 1030;
    float* o1 = o0 + 1030;
    #pragma unroll
    for (int q = 0; q < 2; ++q) {
        int col = colb + q;
        if (col < RD) {
            o0[col]       = xr0[q];
            o0[530 + col] = 1.f - xr0[q];
            o1[col]       = xr1[q];
            o1[530 + col] = 1.f - xr1[q];
        }
    }
    if (wid == 0 && nidx < KD) {
        (myr ? o1 : o0)[500 + nidx] = xs;
    }
}

// ---------------------------------------------------------------------------
extern "C" void kernel_launch(void* const* d_in, const int* in_sizes, int n_in,
                              void* d_out, int out_size, void* d_ws, size_t ws_size,
                              hipStream_t stream)
{
    const float* d   = (const float*)d_in[0];
    const float* W1  = (const float*)d_in[1];
    const float* b1  = (const float*)d_in[2];
    const float* W2  = (const float*)d_in[3];
    const float* b2  = (const float*)d_in[4];
    const float* W3  = (const float*)d_in[5];
    const float* b3  = (const float*)d_in[6];
    const float* Wm  = (const float*)d_in[7];
    const float* cap = (const float*)d_in[8];

    unsigned char* w8 = (unsigned char*)d_ws;
    u16*   h1hi  = (u16*)(w8);                       // 6,553,600 B
    u16*   h1lo  = (u16*)(w8 + 6553600);
    u16*   h2hi  = (u16*)(w8 + 13107200);
    u16*   h2lo  = (u16*)(w8 + 19660800);
    float* part  = (float*)(w8 + 26214400);          // 2 x 1024x512 f32
    float* cost  = (float*)(w8 + 30408704);          // 1024x512 f32
    float* Wpad  = (float*)(w8 + 32505856);
    float* SinvG = (float*)(w8 + 32571392);
    float* c1g   = (float*)(w8 + 32575488);
    float* outp  = (float*)d_out;                    // [1024][1030]

    hipLaunchKernelGGL(prep1, dim3(1), dim3(256), 0, stream, Wm, cap, SinvG, c1g, Wpad);
    // layer 1 (fp32, K=32) -> h1 planes
    hipLaunchKernelGGL(gemm1p, dim3(50,16), dim3(256), 0, stream, d, W1, b1, h1hi, h1lo);
    // layer 2 (MFMA split-bf16): h2 = lrelu(h1 @ W2^T + b2) -> planes
    hipLaunchKernelGGL((mfma_nt<128,0>), dim3(25,8,1), dim3(256), 0, stream,
        h1hi, h1lo, W2, b2, h2hi, h2lo, (float*)nullptr, 3200, 3200, 3200, 3200);
    // layer 3 (MFMA split-bf16, split-K=2): partials = h2 @ W3^T
    hipLaunchKernelGGL((mfma_nt<64,1>), dim3(8,8,2), dim3(256), 0, stream,
        h2hi, h2lo, W3, (const float*)nullptr, (u16*)nullptr, (u16*)nullptr, part,
        3200, 1600, 500, 512);
    hipLaunchKernelGGL(reduce3, dim3(2048), dim3(256), 0, stream, part, b3, cost);
    // 200 ADMM iterations
    hipLaunchKernelGGL(admm4, dim3(512), dim3(256), 0, stream, cost, Wpad, SinvG, c1g, outp);
}

// Round 6
// 749.390 us; speedup vs baseline: 3.2262x; 1.3582x over previous
//
#include <hip/hip_runtime.h>
#include <hip/hip_bf16.h>
#include <cstddef>

#define KD 30      // knapsack constraints
#define KP 32      // padded
#define RD 500     // resources
#define RP 512     // padded
#define NITER 200

typedef unsigned short u16;
typedef __attribute__((ext_vector_type(8))) short short8v;
typedef __attribute__((ext_vector_type(4))) float f32x4;

__device__ inline u16 f2bf(float x) {
    unsigned b = __float_as_uint(x);
    return (u16)((b + 0x7fffu + ((b >> 16) & 1u)) >> 16);
}
__device__ inline float bf2f(u16 u) { return __uint_as_float(((unsigned)u) << 16); }

__device__ inline unsigned cvtpk(float lo, float hi) {
    unsigned r;
    asm("v_cvt_pk_bf16_f32 %0, %1, %2" : "=v"(r) : "v"(lo), "v"(hi));
    return r;
}

// build hi/lo bf16 frags from 8 floats (pair k -> u32 at element 2k) ------
__device__ inline void mkfrag(const float* v, short8v& fh, short8v& fl) {
    union { unsigned u[4]; short8v s; } H, L;
    #pragma unroll
    for (int k = 0; k < 4; ++k) {
        float v0 = v[2*k], v1 = v[2*k+1];
        unsigned uh = cvtpk(v0, v1);
        float h0 = __uint_as_float(uh << 16);
        float h1 = __uint_as_float(uh & 0xffff0000u);
        H.u[k] = uh;
        L.u[k] = cvtpk(v0 - h0, v1 - h1);
    }
    fh = H.s; fl = L.s;
}

__device__ inline void gload_lds16(const void* g, void* l) {
    __builtin_amdgcn_global_load_lds(
        (const __attribute__((address_space(1))) void*)g,
        (__attribute__((address_space(3))) void*)l, 16, 0, 0);
}

// ---------------------------------------------------------------------------
// prep1: S = I + 0.5 W W^T (30x30); SinvG = padded [32][32] S^{-1};
// c1g[m] = rowsum(W)[m] - 2*cap[m] (zero-padded)
// ---------------------------------------------------------------------------
__global__ __launch_bounds__(256) void prep1(
    const float* __restrict__ W, const float* __restrict__ cap,
    float* __restrict__ SinvG, float* __restrict__ c1g)
{
    __shared__ float S[KD][KD];
    __shared__ float Inv[KD][KD];
    int tid = threadIdx.x;
    for (int p = tid; p < KD*KD; p += 256) {
        int a = p / KD, b = p % KD;
        float s = 0.f;
        for (int r = 0; r < RD; ++r) s = fmaf(W[a*RD+r], W[b*RD+r], s);
        S[a][b]  = 0.5f*s + (a==b ? 1.f : 0.f);
        Inv[a][b] = (a==b) ? 1.f : 0.f;
    }
    __syncthreads();
    for (int p = 0; p < KD; ++p) {
        float f = 0.f;
        if (tid < KD && tid != p) f = S[tid][p] / S[p][p];
        __syncthreads();
        if (tid < KD && tid != p) {
            for (int c = 0; c < KD; ++c) {
                S[tid][c]   -= f * S[p][c];
                Inv[tid][c] -= f * Inv[p][c];
            }
        }
        __syncthreads();
    }
    for (int p = tid; p < KP*KP; p += 256) {
        int a2 = p >> 5, b2 = p & 31;
        SinvG[p] = (a2 < KD && b2 < KD) ? Inv[a2][b2] / S[a2][a2] : 0.f;
    }
    if (tid < KP) {
        float s = 0.f;
        if (tid < KD) {
            for (int r = 0; r < RD; ++r) s += W[tid*RD+r];
            s -= 2.f*cap[tid];
        }
        c1g[tid] = s;
    }
}

// ---------------------------------------------------------------------------
// prep2frags: build static MFMA fragments for admm5.
//  fragP: A of P-GEMM (P^T = W a^T):  [w][s][ct][pl][lane][e]
//     value = W[ ct*16+(lane&15) ][ 64w + 4g + 16*(2s+(e>>2)) + (e&3) ]
//  fragG: A of g-GEMM (g^T = W^T y1^T): [w][mt][pl][lane][e]
//     value = W[ 4g + 16*(e>>2) + (e&3) ][ 64w + mt*16 + (lane&15) ]
//  fragS: A of S-GEMM (y1^T = Sinv t^T): [ct2][pl][lane][e]
//     value = SinvG[ ct2*16+(lane&15) ][ 4g + 16*(e>>2) + (e&3) ]
// hi/lo split built pairwise with cvtpk (same pairing as kernel-side mkfrag)
// with a convention-immune residual selection.
// ---------------------------------------------------------------------------
__global__ __launch_bounds__(256) void prep2frags(
    const float* __restrict__ W, const float* __restrict__ SinvG,
    u16* __restrict__ fragP, u16* __restrict__ fragG, u16* __restrict__ fragS)
{
    int idx = blockIdx.x*256 + threadIdx.x;
    if (idx >= 8192 + 8192 + 512) return;
    float v[2];
    u16* basehi; u16* baselo; int pos;   // short positions, pos = element 2k
    if (idx < 8192) {          // P
        int k2 = idx & 3, lane = (idx>>2)&63, ct = (idx>>8)&1, s = (idx>>9)&1, w = idx>>10;
        int g = lane>>4, con = ct*16 + (lane&15);
        #pragma unroll
        for (int h = 0; h < 2; ++h) {
            int e = 2*k2 + h;
            int colpos = 64*w + 4*g + 16*(2*s + (e>>2)) + (e&3);
            v[h] = (con < KD && colpos < RD) ? W[con*RD + colpos] : 0.f;
        }
        int idx4 = (w*2+s)*2+ct;
        basehi = fragP + (idx4*2+0)*512;
        baselo = fragP + (idx4*2+1)*512;
        pos = lane*8 + 2*k2;
    } else if (idx < 16384) {  // G
        int i2 = idx - 8192;
        int k2 = i2 & 3, lane = (i2>>2)&63, mt = (i2>>8)&3, w = i2>>10;
        int g = lane>>4, colpos = 64*w + mt*16 + (lane&15);
        #pragma unroll
        for (int h = 0; h < 2; ++h) {
            int e = 2*k2 + h;
            int con = 4*g + 16*(e>>2) + (e&3);
            v[h] = (con < KD && colpos < RD) ? W[con*RD + colpos] : 0.f;
        }
        int idxg = w*4+mt;
        basehi = fragG + (idxg*2+0)*512;
        baselo = fragG + (idxg*2+1)*512;
        pos = lane*8 + 2*k2;
    } else {                   // S
        int i3 = idx - 16384;
        int k2 = i3 & 3, lane = (i3>>2)&63, ct2 = i3>>8;
        int g = lane>>4, row = ct2*16 + (lane&15);
        #pragma unroll
        for (int h = 0; h < 2; ++h) {
            int e = 2*k2 + h;
            int con = 4*g + 16*(e>>2) + (e&3);
            v[h] = SinvG[row*32 + con];
        }
        basehi = fragS + (ct2*2+0)*512;
        baselo = fragS + (ct2*2+1)*512;
        pos = lane*8 + 2*k2;
    }
    unsigned uh = cvtpk(v[0], v[1]);
    // convention-immune residuals: pick the half that leaves the tiny residual
    float ca = __uint_as_float(uh << 16), cb = __uint_as_float(uh & 0xffff0000u);
    float r0a = v[0] - ca, r0b = v[0] - cb;
    float r1a = v[1] - cb, r1b = v[1] - ca;
    float r0 = (fabsf(r0a) <= fabsf(r0b)) ? r0a : r0b;
    float r1 = (fabsf(r1a) <= fabsf(r1b)) ? r1a : r1b;
    unsigned ul = cvtpk(r0, r1);
    *(unsigned*)(basehi + pos) = uh;
    *(unsigned*)(baselo + pos) = ul;
}

// ---------------------------------------------------------------------------
// convW: fp32 [Nrows][K] -> bf16 hi/lo planes [Npad][K] (pad rows zeroed)
// ---------------------------------------------------------------------------
__global__ __launch_bounds__(256) void convW(
    const float* __restrict__ src, u16* __restrict__ hi, u16* __restrict__ lo,
    int Nrows, int K)
{
    int col = blockIdx.x*256 + threadIdx.x;
    int row = blockIdx.y;
    if (col >= K) return;
    float v = (row < Nrows) ? src[(size_t)row*K + col] : 0.f;
    u16 h = f2bf(v);
    u16 l2 = f2bf(v - bf2f(h));
    size_t o = (size_t)row*K + col;
    hi[o] = h; lo[o] = l2;
}

// ---------------------------------------------------------------------------
// gemm1p: h1 = lrelu(d[1024][32] @ W1[3200][32]^T + b1) -> bf16 hi/lo planes
// ---------------------------------------------------------------------------
__global__ __launch_bounds__(256) void gemm1p(
    const float* __restrict__ A, const float* __restrict__ B,
    const float* __restrict__ bias, u16* __restrict__ Chi, u16* __restrict__ Clo)
{
    __shared__ float As[32][64];
    __shared__ float Bs[32][64];
    int tid = threadIdx.x;
    int bm = blockIdx.y << 6, bn = blockIdx.x << 6;
    int r = tid & 63, kq = (tid >> 6) << 3;
    {
        const float* ap = A + (size_t)(bm + r)*32 + kq;
        const float* bp = B + (size_t)(bn + r)*32 + kq;
        float a8[8], b8[8];
        *(float4*)&a8[0] = *(const float4*)ap;  *(float4*)&a8[4] = *(const float4*)(ap+4);
        *(float4*)&b8[0] = *(const float4*)bp;  *(float4*)&b8[4] = *(const float4*)(bp+4);
        #pragma unroll
        for (int i = 0; i < 8; ++i) { As[kq+i][r] = a8[i]; Bs[kq+i][r] = b8[i]; }
    }
    __syncthreads();
    int m0 = (tid >> 4) << 2, n0 = (tid & 15) << 2;
    float acc[4][4];
    #pragma unroll
    for (int i = 0; i < 4; ++i)
        #pragma unroll
        for (int j = 0; j < 4; ++j) acc[i][j] = 0.f;
    #pragma unroll
    for (int kk = 0; kk < 32; ++kk) {
        float a4[4], b4[4];
        *(float4*)a4 = *(const float4*)&As[kk][m0];
        *(float4*)b4 = *(const float4*)&Bs[kk][n0];
        #pragma unroll
        for (int i = 0; i < 4; ++i)
            #pragma unroll
            for (int j = 0; j < 4; ++j)
                acc[i][j] = fmaf(a4[i], b4[j], acc[i][j]);
    }
    #pragma unroll
    for (int i = 0; i < 4; ++i) {
        #pragma unroll
        for (int j = 0; j < 4; ++j) {
            int col = bn + n0 + j;
            float v = acc[i][j] + bias[col];
            v = v > 0.f ? v : 0.1f*v;
            u16 h = f2bf(v);
            u16 l2 = f2bf(v - bf2f(h));
            size_t o = (size_t)(bm + m0 + i)*3200 + col;
            Chi[o] = h; Clo[o] = l2;
        }
    }
}

// ---------------------------------------------------------------------------
// mfma_nt: C = A @ B^T. A = bf16 hi/lo planes [M][Kfull].
// BSRC=0: B fp32 [Nrows][Kfull], converted on the fly.
// BSRC=1: B = bf16 hi/lo planes (rows pre-padded/zeroed), global_load_lds.
// Split: hi*hi + hi*lo + lo*hi. BM=128, BN=128/64, BK=32, 4 waves, dbuf LDS.
// OM=0: lrelu+bias -> bf16 planes. OM=1: raw fp32 partial (split-K via z).
// ---------------------------------------------------------------------------
template<int BN, int OM, int BSRC>
__global__ __launch_bounds__(256) void mfma_nt(
    const u16* __restrict__ Ahi, const u16* __restrict__ Alo,
    const float* __restrict__ Bf,
    const u16* __restrict__ Bhi, const u16* __restrict__ Blo,
    const float* __restrict__ bias,
    u16* __restrict__ Chi, u16* __restrict__ Clo, float* __restrict__ Cf,
    int Kfull, int kLen, int Nrows, int ldo)
{
    constexpr int BK = 32;
    constexpr int NTN = (BN == 128) ? 4 : 2;
    constexpr int NB  = (BN == 128) ? 16 : 8;
    __shared__ __align__(16) u16 Ah[2][4096], Al[2][4096];
    __shared__ __align__(16) u16 Bh[2][BN*BK], Bl[2][BN*BK];

    const int tid = threadIdx.x, lane = tid & 63, w = tid >> 6;
    const int lr = lane & 15, lk = lane >> 4;
    const int bm = blockIdx.y << 7;
    const int bn = blockIdx.x * BN;
    const int wm = w >> 1, wn = w & 1;
    const int kOff = blockIdx.z * kLen;
    const int NTS = kLen / BK;

    f32x4 acc[4][NTN];
    #pragma unroll
    for (int i = 0; i < 4; ++i)
        #pragma unroll
        for (int j = 0; j < NTN; ++j) acc[i][j] = (f32x4){0.f, 0.f, 0.f, 0.f};

    // on-the-fly B staging geometry (BSRC=0)
    int brow, bko, bchunk0;
    if (BN == 128) { brow = w*32 + (lane & 31); bko = (lane >> 5) * 16; bchunk0 = ((lane >> 5)*2)*128 + brow; }
    else           { brow = w*16 + (lane & 15); bko = (lane >> 4) * 8;  bchunk0 = (lane >> 4)*64  + brow; }
    const float* bptr = Bf + (size_t)(bn + brow)*Kfull + kOff + bko;
    const bool bok = (bn + brow) < Nrows;

    // plane B staging geometry (BSRC=1): chunkid = w*BN + c*64 + lane
    int bq0 = 0, br0 = 0;
    if (BSRC == 1) {
        int cid = w*BN + lane;
        bq0 = cid / BN; br0 = cid % BN;   // only first call's decode; BN=128 second call below
    }

    const u16* ahp = Ahi + (size_t)(bm + lane)*Kfull + kOff + 8*w;
    const u16* alp = Alo + (size_t)(bm + lane)*Kfull + kOff + 8*w;
    const size_t arstride = (size_t)64 * Kfull;

    auto stageA = [&](int buf, int t) {
        int k0 = t * BK;
        gload_lds16(ahp + k0,            &Ah[buf][(w*128     ) * 8]);
        gload_lds16(ahp + k0 + arstride, &Ah[buf][(w*128 + 64) * 8]);
        gload_lds16(alp + k0,            &Al[buf][(w*128     ) * 8]);
        gload_lds16(alp + k0 + arstride, &Al[buf][(w*128 + 64) * 8]);
    };
    auto stageBpre = [&](int buf, int t) {
        int k0 = kOff + t * BK;
        {
            const u16* sh = Bhi + (size_t)(bn + br0)*Kfull + k0 + bq0*8;
            const u16* sl = Blo + (size_t)(bn + br0)*Kfull + k0 + bq0*8;
            gload_lds16(sh, &Bh[buf][(w*BN) * 8]);
            gload_lds16(sl, &Bl[buf][(w*BN) * 8]);
        }
        if (BN == 128) {
            int cid = w*BN + 64 + lane;
            int q = cid >> 7, rr = cid & 127;
            const u16* sh = Bhi + (size_t)(bn + rr)*Kfull + k0 + q*8;
            const u16* sl = Blo + (size_t)(bn + rr)*Kfull + k0 + q*8;
            gload_lds16(sh, &Bh[buf][(w*BN + 64) * 8]);
            gload_lds16(sl, &Bl[buf][(w*BN + 64) * 8]);
        }
    };
    auto loadB = [&](int t, float (&arr)[NB]) {
        #pragma unroll
        for (int i = 0; i < NB; i += 4)
            *(float4*)&arr[i] = bok ? *(const float4*)(bptr + t*BK + i)
                                    : make_float4(0.f, 0.f, 0.f, 0.f);
    };
    auto writeB = [&](int buf, float (&arr)[NB]) {
        u16 hh[NB], ll[NB];
        #pragma unroll
        for (int i = 0; i < NB; ++i) {
            hh[i] = f2bf(arr[i]);
            ll[i] = f2bf(arr[i] - bf2f(hh[i]));
        }
        #pragma unroll
        for (int c = 0; c < NB/8; ++c) {
            short8v vh, vl;
            #pragma unroll
            for (int j = 0; j < 8; ++j) { vh[j] = (short)hh[c*8+j]; vl[j] = (short)ll[c*8+j]; }
            int ch = bchunk0 + c*128;
            *(short8v*)&Bh[buf][ch*8] = vh;
            *(short8v*)&Bl[buf][ch*8] = vl;
        }
    };
    auto compute = [&](int buf) {
        short8v ah[4], al[4];
        #pragma unroll
        for (int mt = 0; mt < 4; ++mt) {
            int c = (lk*128 + wm*64 + mt*16 + lr) * 8;
            ah[mt] = *(const short8v*)&Ah[buf][c];
            al[mt] = *(const short8v*)&Al[buf][c];
        }
        #pragma unroll
        for (int nt = 0; nt < NTN; ++nt) {
            int c = (lk*BN + wn*(NTN*16) + nt*16 + lr) * 8;
            short8v bh = *(const short8v*)&Bh[buf][c];
            short8v bl = *(const short8v*)&Bl[buf][c];
            #pragma unroll
            for (int mt = 0; mt < 4; ++mt) {
                acc[mt][nt] = __builtin_amdgcn_mfma_f32_16x16x32_bf16(ah[mt], bh, acc[mt][nt], 0, 0, 0);
                acc[mt][nt] = __builtin_amdgcn_mfma_f32_16x16x32_bf16(ah[mt], bl, acc[mt][nt], 0, 0, 0);
                acc[mt][nt] = __builtin_amdgcn_mfma_f32_16x16x32_bf16(al[mt], bh, acc[mt][nt], 0, 0, 0);
            }
        }
    };

    float bcur[NB], bnxt[NB];
    stageA(0, 0);
    if (BSRC == 1) stageBpre(0, 0);
    else { loadB(0, bcur); writeB(0, bcur); }
    int cur = 0;
    for (int t = 0; t < NTS; ++t) {
        __syncthreads();
        if (t + 1 < NTS) {
            stageA(cur ^ 1, t + 1);
            if (BSRC == 1) stageBpre(cur ^ 1, t + 1);
            else loadB(t + 1, bnxt);
        }
        compute(cur);
        if (BSRC == 0 && t + 1 < NTS) writeB(cur ^ 1, bnxt);
        cur ^= 1;
    }

    if (OM == 0) {
        #pragma unroll
        for (int nt = 0; nt < NTN; ++nt) {
            int col = bn + wn*(NTN*16) + nt*16 + lr;
            float bia = bias[col];
            #pragma unroll
            for (int mt = 0; mt < 4; ++mt) {
                #pragma unroll
                for (int j = 0; j < 4; ++j) {
                    int row = bm + wm*64 + mt*16 + lk*4 + j;
                    float v = acc[mt][nt][j] + bia;
                    v = v > 0.f ? v : 0.1f*v;
                    u16 h = f2bf(v);
                    u16 l2 = f2bf(v - bf2f(h));
                    size_t o = (size_t)row*ldo + col;
                    Chi[o] = h; Clo[o] = l2;
                }
            }
        }
    } else {
        float* cf = Cf + (size_t)blockIdx.z * (1024*512);
        #pragma unroll
        for (int nt = 0; nt < NTN; ++nt) {
            int col = bn + wn*(NTN*16) + nt*16 + lr;
            #pragma unroll
            for (int mt = 0; mt < 4; ++mt) {
                #pragma unroll
                for (int j = 0; j < 4; ++j) {
                    int row = bm + wm*64 + mt*16 + lk*4 + j;
                    cf[(size_t)row*ldo + col] = acc[mt][nt][j];
                }
            }
        }
    }
}

// ---------------------------------------------------------------------------
// reduce3: cost[1024][512] = sum_sk partials + b3 (cols<500), else 0
// ---------------------------------------------------------------------------
__global__ __launch_bounds__(256) void reduce3(
    const float* __restrict__ part, const float* __restrict__ b3,
    float* __restrict__ cost)
{
    int i = blockIdx.x*256 + threadIdx.x;
    int col = i & 511;
    float v = part[i] + part[i + 524288];
    cost[i] = (col < RD) ? v + b3[col] : 0.f;
}

// ---------------------------------------------------------------------------
// admm5: MFMA-based q-form ADMM. 64 blocks x 512 thr; block = 16 batch rows;
// wave w owns col-positions [64w, 64w+64). Lane (row=l&15, g=l>>4) owns state
// slots (m<4, j<4) -> col p = 64w + 4g + 16m + j; qs slots e -> con
// 4g+16(e>>2)+(e&3).
//   a = 0.5(w+|qr|-|qt|)                                   (regs)
//   P^T = W a^T        (12 MFMA, static fragP in VGPRs)
//   t = reduce_waves(P) + |qs| + c1                        (LDS, 2 barriers)
//   y1^T = Sinv t^T    (6 MFMA, fragS)
//   g^T = W^T y1^T     (12 MFMA, fragG)
//   x_r = 0.5a - 0.25g + 0.5; x_t = 1-x_r; x_s = 0.5(|qs|-y1); q <- x+min(q,0)
// qs replicated across waves (deterministic); only wave 0 writes x_s.
// ---------------------------------------------------------------------------
__global__ __launch_bounds__(512) void admm5(
    const float* __restrict__ cost, const u16* __restrict__ fragP,
    const u16* __restrict__ fragG, const u16* __restrict__ fragS,
    const float* __restrict__ c1g, float* __restrict__ out)
{
    __shared__ float red[8][16][33];
    __shared__ float tb[16][33];

    const int tid = threadIdx.x, lane = tid & 63, w = tid >> 6;
    const int g = lane >> 4, row = lane & 15;
    const int blockRow = blockIdx.x << 4;

    // static fragments
    short8v WP[2][2][2], WG[4][2], SV[2][2];
    #pragma unroll
    for (int s = 0; s < 2; ++s)
        #pragma unroll
        for (int ct = 0; ct < 2; ++ct)
            #pragma unroll
            for (int pl = 0; pl < 2; ++pl)
                WP[s][ct][pl] = *(const short8v*)(fragP + ((((w*2+s)*2+ct)*2+pl)*64 + lane)*8);
    #pragma unroll
    for (int mt = 0; mt < 4; ++mt)
        #pragma unroll
        for (int pl = 0; pl < 2; ++pl)
            WG[mt][pl] = *(const short8v*)(fragG + (((w*4+mt)*2+pl)*64 + lane)*8);
    #pragma unroll
    for (int ct = 0; ct < 2; ++ct)
        #pragma unroll
        for (int pl = 0; pl < 2; ++pl)
            SV[ct][pl] = *(const short8v*)(fragS + ((ct*2+pl)*64 + lane)*8);

    float c1s[8];
    #pragma unroll
    for (int e = 0; e < 8; ++e) {
        int con = 4*g + 16*(e>>2) + (e&3);
        c1s[e] = (con < KD) ? c1g[con] : 0.f;
    }

    float wr[4][4];
    #pragma unroll
    for (int m = 0; m < 4; ++m)
        *(float4*)&wr[m][0] = *(const float4*)(cost + (size_t)(blockRow + row)*RP + 64*w + 4*g + 16*m);

    float qr[4][4], qt[4][4], qs[8], xs[8];
    #pragma unroll
    for (int m = 0; m < 4; ++m)
        #pragma unroll
        for (int j = 0; j < 4; ++j) { qr[m][j] = 0.f; qt[m][j] = 0.f; }
    #pragma unroll
    for (int e = 0; e < 8; ++e) { qs[e] = 0.f; xs[e] = 0.f; }

    float a[4][4];
    f32x4 accG[4];

    #pragma unroll 1
    for (int it = 0; it < NITER; ++it) {
        #pragma unroll
        for (int m = 0; m < 4; ++m)
            #pragma unroll
            for (int j = 0; j < 4; ++j)
                a[m][j] = 0.5f * ((wr[m][j] + fabsf(qr[m][j])) - fabsf(qt[m][j]));

        // a-frags: frag s element e = a[2s+(e>>2)][e&3]
        short8v afh[2], afl[2];
        mkfrag(&a[0][0], afh[0], afl[0]);
        mkfrag(&a[2][0], afh[1], afl[1]);

        // P-GEMM
        f32x4 accP[2];
        #pragma unroll
        for (int ct = 0; ct < 2; ++ct) accP[ct] = (f32x4){0.f,0.f,0.f,0.f};
        #pragma unroll
        for (int ct = 0; ct < 2; ++ct)
            #pragma unroll
            for (int s = 0; s < 2; ++s) {
                accP[ct] = __builtin_amdgcn_mfma_f32_16x16x32_bf16(WP[s][ct][0], afh[s], accP[ct], 0,0,0);
                accP[ct] = __builtin_amdgcn_mfma_f32_16x16x32_bf16(WP[s][ct][0], afl[s], accP[ct], 0,0,0);
                accP[ct] = __builtin_amdgcn_mfma_f32_16x16x32_bf16(WP[s][ct][1], afh[s], accP[ct], 0,0,0);
            }
        // partial writes: D element j of tile ct -> con ct*16+4g+j
        #pragma unroll
        for (int ct = 0; ct < 2; ++ct)
            #pragma unroll
            for (int j = 0; j < 4; ++j)
                red[w][row][ct*16 + 4*g + j] = accP[ct][j];
        __syncthreads();
        // stage-1: thread owns slot (srow, scon)
        {
            int srow = tid >> 5, scon = tid & 31;
            float s = red[0][srow][scon];
            #pragma unroll
            for (int w2 = 1; w2 < 8; ++w2) s += red[w2][srow][scon];
            tb[srow][scon] = s;
        }
        __syncthreads();
        // t-hat B-frag (+ es + c1, replicated identically in every wave)
        float th[8];
        #pragma unroll
        for (int e = 0; e < 8; ++e)
            th[e] = tb[row][4*g + 16*(e>>2) + (e&3)] + fabsf(qs[e]) + c1s[e];
        short8v tfh, tfl;
        mkfrag(th, tfh, tfl);
        // S-GEMM
        f32x4 accS[2];
        #pragma unroll
        for (int ct = 0; ct < 2; ++ct) {
            f32x4 acc2 = (f32x4){0.f,0.f,0.f,0.f};
            acc2 = __builtin_amdgcn_mfma_f32_16x16x32_bf16(SV[ct][0], tfh, acc2, 0,0,0);
            acc2 = __builtin_amdgcn_mfma_f32_16x16x32_bf16(SV[ct][0], tfl, acc2, 0,0,0);
            acc2 = __builtin_amdgcn_mfma_f32_16x16x32_bf16(SV[ct][1], tfh, acc2, 0,0,0);
            accS[ct] = acc2;
        }
        float y1[8];
        #pragma unroll
        for (int e = 0; e < 8; ++e) y1[e] = accS[e>>2][e&3];
        short8v yfh, yfl;
        mkfrag(y1, yfh, yfl);
        // g-GEMM
        #pragma unroll
        for (int mt = 0; mt < 4; ++mt) {
            f32x4 acc2 = (f32x4){0.f,0.f,0.f,0.f};
            acc2 = __builtin_amdgcn_mfma_f32_16x16x32_bf16(WG[mt][0], yfh, acc2, 0,0,0);
            acc2 = __builtin_amdgcn_mfma_f32_16x16x32_bf16(WG[mt][0], yfl, acc2, 0,0,0);
            acc2 = __builtin_amdgcn_mfma_f32_16x16x32_bf16(WG[mt][1], yfh, acc2, 0,0,0);
            accG[mt] = acc2;
        }
        // updates
        #pragma unroll
        for (int m = 0; m < 4; ++m)
            #pragma unroll
            for (int j = 0; j < 4; ++j) {
                float x = fmaf(accG[m][j], -0.25f, fmaf(a[m][j], 0.5f, 0.5f));
                qr[m][j] = x + fminf(qr[m][j], 0.f);
                qt[m][j] = (1.f - x) + fminf(qt[m][j], 0.f);
            }
        #pragma unroll
        for (int e = 0; e < 8; ++e) {
            xs[e] = 0.5f * (fabsf(qs[e]) - y1[e]);
            qs[e] = xs[e] + fminf(qs[e], 0.f);
        }
    }

    // output: x of the final iteration (recompute from last a, accG)
    float* orow = out + (size_t)(blockRow + row) * 1030;
    #pragma unroll
    for (int m = 0; m < 4; ++m)
        #pragma unroll
        for (int j = 0; j < 4; ++j) {
            int p = 64*w + 4*g + 16*m + j;
            if (p < RD) {
                float x = fmaf(accG[m][j], -0.25f, fmaf(a[m][j], 0.5f, 0.5f));
                orow[p]       = x;
                orow[530 + p] = 1.f - x;
            }
        }
    if (w == 0) {
        #pragma unroll
        for (int e = 0; e < 8; ++e) {
            int con = 4*g + 16*(e>>2) + (e&3);
            if (con < KD) orow[500 + con] = xs[e];
        }
    }
}

// ---------------------------------------------------------------------------
extern "C" void kernel_launch(void* const* d_in, const int* in_sizes, int n_in,
                              void* d_out, int out_size, void* d_ws, size_t ws_size,
                              hipStream_t stream)
{
    const float* d   = (const float*)d_in[0];
    const float* W1  = (const float*)d_in[1];
    const float* b1  = (const float*)d_in[2];
    const float* W2  = (const float*)d_in[3];
    const float* b2  = (const float*)d_in[4];
    const float* W3  = (const float*)d_in[5];
    const float* b3  = (const float*)d_in[6];
    const float* Wm  = (const float*)d_in[7];
    const float* cap = (const float*)d_in[8];

    unsigned char* w8 = (unsigned char*)d_ws;
    u16*   h1hi  = (u16*)(w8);
    u16*   h1lo  = (u16*)(w8 + 6553600);
    u16*   h2hi  = (u16*)(w8 + 13107200);
    u16*   h2lo  = (u16*)(w8 + 19660800);
    float* part  = (float*)(w8 + 26214400);          // 2 x 1024x512 f32
    float* cost  = (float*)(w8 + 30408704);          // 1024x512 f32
    float* SinvG = (float*)(w8 + 32505856);          // 32x32 f32
    float* c1g   = (float*)(w8 + 32509952);          // 32 f32
    u16*   fragP = (u16*)(w8 + 32510208);            // 65536 B
    u16*   fragG = (u16*)(w8 + 32575744);            // 65536 B
    u16*   fragS = (u16*)(w8 + 32641280);            // 4096 B
    // gated preconverted weight planes
    u16*   w2hi  = (u16*)(w8 + 32645632);            // 3200x3200 bf16
    u16*   w2lo  = (u16*)(w8 + 53125632);
    u16*   w3hi  = (u16*)(w8 + 73605632);            // 512x3200 bf16 (padded)
    u16*   w3lo  = (u16*)(w8 + 76882432);
    const size_t pre_need = 80159232;
    const bool pre = (ws_size >= pre_need);
    float* outp  = (float*)d_out;

    hipLaunchKernelGGL(prep1, dim3(1), dim3(256), 0, stream, Wm, cap, SinvG, c1g);
    hipLaunchKernelGGL(prep2frags, dim3(66), dim3(256), 0, stream, Wm, SinvG, fragP, fragG, fragS);
    hipLaunchKernelGGL(gemm1p, dim3(50,16), dim3(256), 0, stream, d, W1, b1, h1hi, h1lo);

    if (pre) {
        hipLaunchKernelGGL(convW, dim3(13,3200), dim3(256), 0, stream, W2, w2hi, w2lo, 3200, 3200);
        hipLaunchKernelGGL(convW, dim3(13,512),  dim3(256), 0, stream, W3, w3hi, w3lo, 500,  3200);
        hipLaunchKernelGGL((mfma_nt<128,0,1>), dim3(25,8,1), dim3(256), 0, stream,
            h1hi, h1lo, (const float*)nullptr, w2hi, w2lo, b2,
            h2hi, h2lo, (float*)nullptr, 3200, 3200, 3200, 3200);
        hipLaunchKernelGGL((mfma_nt<64,1,1>), dim3(8,8,2), dim3(256), 0, stream,
            h2hi, h2lo, (const float*)nullptr, w3hi, w3lo, (const float*)nullptr,
            (u16*)nullptr, (u16*)nullptr, part, 3200, 1600, 500, 512);
    } else {
        hipLaunchKernelGGL((mfma_nt<128,0,0>), dim3(25,8,1), dim3(256), 0, stream,
            h1hi, h1lo, W2, (const u16*)nullptr, (const u16*)nullptr, b2,
            h2hi, h2lo, (float*)nullptr, 3200, 3200, 3200, 3200);
        hipLaunchKernelGGL((mfma_nt<64,1,0>), dim3(8,8,2), dim3(256), 0, stream,
            h2hi, h2lo, W3, (const u16*)nullptr, (const u16*)nullptr, (const float*)nullptr,
            (u16*)nullptr, (u16*)nullptr, part, 3200, 1600, 500, 512);
    }
    hipLaunchKernelGGL(reduce3, dim3(2048), dim3(256), 0, stream, part, b3, cost);
    hipLaunchKernelGGL(admm5, dim3(64), dim3(512), 0, stream, cost, fragP, fragG, fragS, c1g, outp);
}